// Round 8
// baseline (318.894 us; speedup 1.0000x reference)
//
#include <hip/hip_runtime.h>
#include <hip/hip_fp16.h>

// ---------------------------------------------------------------------------
// GATv2 x2 + classifier. N=50000, E=800000, IN=128, HEADS=4, HID=32, OUT=16.
// R18: (a) scatter role-split removed -- scatter EMBEDDED in gemm blocks.
//      R17's 1024 scatter-role blocks each allocated the kernel's 40KB LDS
//      (4 blocks/CU ceiling) for ~3-5us of real work. Now: 784-block grid,
//      slice = blockIdx&7 (XCD binding kept), rank = blockIdx>>3; 5 edges/
//      thread staged as: prologue bucket loads -> post-kc0 atomics ->
//      post-kc1 csr stores -- every phase hidden under a ~10us K-iteration.
//      (b) scan_bsum merged into scan_add (each block re-scans the 196-entry
//      bsum in LDS; block0 writes the total): one fewer dispatch.
//      KEPT (verified): bucket pre-partition in count pass (FETCH 51->29MB),
//      R10-form attn + separate classifier, h1 fp16, setprio MFMA cluster.
// ---------------------------------------------------------------------------

#define LOG2E 1.4426950408889634f
#define AST 40  // LDS row stride in shorts (80B rows; fragment reads 2-way=free)

typedef short bf16x8 __attribute__((ext_vector_type(8)));
typedef float f32x4 __attribute__((ext_vector_type(4)));

__device__ __forceinline__ unsigned short f2bf(float f) {
  union { float f; unsigned u; } x; x.f = f;
  unsigned r = x.u + 0x7fffu + ((x.u >> 16) & 1u);
  return (unsigned short)(r >> 16);
}
__device__ __forceinline__ float bf2f(unsigned short h) {
  union { unsigned u; float f; } x; x.u = ((unsigned)h) << 16;
  return x.f;
}
__device__ __forceinline__ void split4(float4 v, ushort4& h, ushort4& l) {
  h.x = f2bf(v.x); l.x = f2bf(v.x - bf2f(h.x));
  h.y = f2bf(v.y); l.y = f2bf(v.y - bf2f(h.y));
  h.z = f2bf(v.z); l.z = f2bf(v.z - bf2f(h.z));
  h.w = f2bf(v.w); l.w = f2bf(v.w - bf2f(h.w));
}

// ------------------------------ CSR build ----------------------------------

// per-block scan of (cnt[i]+1)  (+1 = self loop slot)
__global__ __launch_bounds__(256) void scan_blk(const int* __restrict__ cnt,
                                                int* __restrict__ excl,
                                                int* __restrict__ bsum, int n) {
  __shared__ int s[256];
  int t = threadIdx.x, i = blockIdx.x * 256 + t;
  int v = (i < n) ? (cnt[i] + 1) : 0;
  s[t] = v;
  __syncthreads();
#pragma unroll
  for (int off = 1; off < 256; off <<= 1) {
    int u = (t >= off) ? s[t - off] : 0;
    __syncthreads();
    s[t] += u;
    __syncthreads();
  }
  if (i < n) excl[i] = s[t] - v;
  if (t == 255) bsum[blockIdx.x] = s[255];
}

// merged bsum-scan + add: each block scans bsum[0..nb) in LDS (nb<=256),
// takes its own exclusive prefix; writes row_start/wpos/self-loop; block 0
// also writes row_start[n] (total) and zeroes the csr pad.
__global__ __launch_bounds__(256) void scan_add(int* __restrict__ row_start,
                                                const int* __restrict__ bsum,
                                                int* __restrict__ wpos,
                                                int* __restrict__ csr,
                                                int n, int padBase, int nb) {
  __shared__ int s[256];
  int t = threadIdx.x;
  int v = (t < nb) ? bsum[t] : 0;
  s[t] = v;
  __syncthreads();
#pragma unroll
  for (int off = 1; off < 256; off <<= 1) {
    int u = (t >= off) ? s[t - off] : 0;
    __syncthreads();
    s[t] += u;
    __syncthreads();
  }
  int pref = (blockIdx.x > 0) ? s[blockIdx.x - 1] : 0;
  int i = blockIdx.x * 256 + t;
  if (i < n) {
    int r = row_start[i] + pref;
    row_start[i] = r;
    wpos[i] = r + 1;
    csr[r] = i;  // self loop first in each row
  }
  if (blockIdx.x == 0) {
    if (t == 0) row_start[n] = s[nb - 1];
    if (t < 16) csr[padBase + t] = 0;
  }
}

// ------------- weight convert + degree count + slice bucketing -------------
// blocks 0..255: split-bf16 weight transpose (both layers)
// blocks 256.. : 1024 edges each: degree count + append (src,dst) to the
//                dst-slice bucket (LDS histogram -> 1 global cursor
//                atomicAdd per bucket -> contiguous run writes).
#define EPB 1024
__global__ __launch_bounds__(256) void convert_count(
    const float* __restrict__ Wl1, const float* __restrict__ Wr1,
    const float* __restrict__ Wl2, const float* __restrict__ Wr2,
    unsigned short* __restrict__ BT1h, unsigned short* __restrict__ BT1l,
    unsigned short* __restrict__ BT2h, unsigned short* __restrict__ BT2l,
    const int* __restrict__ esrc, const int* __restrict__ edst,
    int* __restrict__ cnt, int* __restrict__ bucketCur,
    int2* __restrict__ bucket, int E, int sliceSize, int cap) {
  int b = blockIdx.x;
  int t = threadIdx.x;
  if (b >= 256) {
    __shared__ int bcnt[8], bbase[8];
    if (t < 8) bcnt[t] = 0;
    __syncthreads();
    int base = (b - 256) * EPB;
    int sl[4], rk[4], dv[4], sv[4];
#pragma unroll
    for (int j = 0; j < 4; ++j) {
      int i = base + t + j * 256;
      bool v = (i < E);
      int d = v ? edst[i] : 0;
      sv[j] = v ? esrc[i] : 0;
      dv[j] = d;
      int s = d / sliceSize;  // 0..7
      sl[j] = v ? s : -1;
      if (v) {
        atomicAdd(&cnt[d], 1);
        rk[j] = atomicAdd(&bcnt[s], 1);
      }
    }
    __syncthreads();
    if (t < 8 && bcnt[t] > 0) bbase[t] = atomicAdd(&bucketCur[t], bcnt[t]);
    __syncthreads();
#pragma unroll
    for (int j = 0; j < 4; ++j) {
      if (sl[j] >= 0) {
        int pos = sl[j] * cap + bbase[sl[j]] + rk[j];
        bucket[pos] = make_int2(sv[j], dv[j]);
      }
    }
    return;
  }
  const float* Wl = (b < 128) ? Wl1 : Wl2;
  const float* Wr = (b < 128) ? Wr1 : Wr2;
  unsigned short* BTh = (b < 128) ? BT1h : BT2h;
  unsigned short* BTl = (b < 128) ? BT1l : BT2l;
  int idx = (b & 127) * 256 + t;  // 0..32767
  int col = idx >> 7, k = idx & 127;
  float v = (col < 128) ? Wl[k * 128 + col] : Wr[k * 128 + (col - 128)];
  unsigned short h = f2bf(v);
  BTh[idx] = h;
  BTl[idx] = f2bf(v - bf2f(h));
}

// --------------------- MFMA GEMM (+embedded scatter) -----------------------
// C[N x 256] = A[N x 128] @ W[128 x 256], split-bf16 3-term; C stored fp16.
// Block = 128 rows x 128 cols. 4 waves, each 64x64 (16 acc tiles).
// FUSE=1: every block ALSO scatters ~per edges of its XCD's slice bucket
// (slice = blockIdx&7, rank = blockIdx>>3). Pipeline: prologue bucket loads
// -> post-kc0 wpos atomics -> post-kc1 csr stores (each phase's latency
// hides under a K-iteration). Blocks beyond the gemm grid scatter and exit.
enum { IN_F32 = 0, IN_F16 = 1 };
#define SJ 5  // scatter edges per thread (covers 1280*blocksPerSlice >= cntS)
template <int MODE, int FUSE>
__global__ __launch_bounds__(256) void gemm_mfma(
    const float* __restrict__ Af, const __half* __restrict__ Af16,
    const unsigned short* __restrict__ BTh, const unsigned short* __restrict__ BTl,
    __half* __restrict__ Cl, __half* __restrict__ Cr, int nrows,
    const int2* __restrict__ bucket, const int* __restrict__ bucketCur,
    int* __restrict__ wpos, int* __restrict__ csr, int cap) {
  __shared__ __align__(16) unsigned short smem[4 * 128 * AST];
  int tid = threadIdx.x;
  int bx, by;
  int2 ebuf[SJ];
  int epos[SJ];
  if (FUSE) {
    int gid = blockIdx.x;
    int slice = gid & 7;   // == XCD (round-robin dispatch)
    int rank = gid >> 3;
    int nbs = (int)(gridDim.x >> 3);  // blocks per slice
    int cntS = bucketCur[slice];
    int per = (cntS + nbs - 1) / nbs;
    int b0 = rank * per;
    int ee = min(b0 + per, cntS);
    const int2* bk = bucket + (size_t)slice * cap;
#pragma unroll
    for (int j = 0; j < SJ; ++j) {
      int idx = b0 + tid + j * 256;
      ebuf[j] = (idx < ee) ? bk[idx] : make_int2(0, -1);
    }
    int nbx = (nrows + 127) >> 7;
    if (gid >= nbx * 2) {  // scatter-only tail block
#pragma unroll
      for (int j = 0; j < SJ; ++j)
        if (ebuf[j].y >= 0) {
          int p = atomicAdd(&wpos[ebuf[j].y], 1);
          csr[p] = ebuf[j].x;
        }
      return;
    }
    bx = gid >> 1;
    by = gid & 1;
  } else {
    bx = blockIdx.x;
    by = blockIdx.y;
  }

  unsigned short* sAh = smem;
  unsigned short* sAl = smem + 5120;
  unsigned short* sBh = smem + 10240;
  unsigned short* sBl = smem + 15360;

  int wave = tid >> 6, lane = tid & 63;
  int rowBase = bx * 128;
  int colBase = by * 128;
  int rowHalf = (wave >> 1) * 64;
  int colHalf = (wave & 1) * 64;
  int l15 = lane & 15, quad = lane >> 4;

  f32x4 acc[4][4];
#pragma unroll
  for (int m = 0; m < 4; ++m)
#pragma unroll
    for (int n = 0; n < 4; ++n) acc[m][n] = (f32x4){0.f, 0.f, 0.f, 0.f};

  for (int kc = 0; kc < 4; ++kc) {
    // stage A: 128 rows x 32 k (hi+lo); idx 0..511, 8 k-elems each
#pragma unroll
    for (int i = 0; i < 2; ++i) {
      int idx = tid + i * 256;
      int row = idx >> 2, seg = idx & 3;
      int gr = rowBase + row;
      float4 v0 = make_float4(0.f, 0.f, 0.f, 0.f), v1 = v0;
      if (MODE == IN_F32) {
        if (gr < nrows) {
          v0 = *(const float4*)&Af[(size_t)gr * 128 + kc * 32 + seg * 8];
          v1 = *(const float4*)&Af[(size_t)gr * 128 + kc * 32 + seg * 8 + 4];
        }
      } else {
        if (gr < nrows) {
          uint4 raw = *(const uint4*)&Af16[(size_t)gr * 128 + kc * 32 + seg * 8];
          const __half* hp = (const __half*)&raw;
          v0 = make_float4(__half2float(hp[0]), __half2float(hp[1]),
                           __half2float(hp[2]), __half2float(hp[3]));
          v1 = make_float4(__half2float(hp[4]), __half2float(hp[5]),
                           __half2float(hp[6]), __half2float(hp[7]));
        }
      }
      ushort4 h0, l0, h1, l1;
      split4(v0, h0, l0);
      split4(v1, h1, l1);
      *(ushort4*)&sAh[row * AST + seg * 8] = h0;
      *(ushort4*)&sAh[row * AST + seg * 8 + 4] = h1;
      *(ushort4*)&sAl[row * AST + seg * 8] = l0;
      *(ushort4*)&sAl[row * AST + seg * 8 + 4] = l1;
    }
    // stage B: 128 cols x 32 k (hi+lo); idx 0..511
#pragma unroll
    for (int i = 0; i < 2; ++i) {
      int idx = tid + i * 256;
      int col = idx >> 2, seg = idx & 3;
      *(uint4*)&sBh[col * AST + seg * 8] =
          *(const uint4*)&BTh[(size_t)(colBase + col) * 128 + kc * 32 + seg * 8];
      *(uint4*)&sBl[col * AST + seg * 8] =
          *(const uint4*)&BTl[(size_t)(colBase + col) * 128 + kc * 32 + seg * 8];
    }
    __syncthreads();

    bf16x8 afh[4], afl[4], bfh[4], bfl[4];
#pragma unroll
    for (int m = 0; m < 4; ++m) {
      int r = rowHalf + m * 16 + l15;
      afh[m] = *(const bf16x8*)&sAh[r * AST + quad * 8];
      afl[m] = *(const bf16x8*)&sAl[r * AST + quad * 8];
    }
#pragma unroll
    for (int n = 0; n < 4; ++n) {
      int cc = colHalf + n * 16 + l15;
      bfh[n] = *(const bf16x8*)&sBh[cc * AST + quad * 8];
      bfl[n] = *(const bf16x8*)&sBl[cc * AST + quad * 8];
    }
    __builtin_amdgcn_s_setprio(1);
#pragma unroll
    for (int m = 0; m < 4; ++m)
#pragma unroll
      for (int n = 0; n < 4; ++n) {
        acc[m][n] = __builtin_amdgcn_mfma_f32_16x16x32_bf16(afh[m], bfh[n], acc[m][n], 0, 0, 0);
        acc[m][n] = __builtin_amdgcn_mfma_f32_16x16x32_bf16(afh[m], bfl[n], acc[m][n], 0, 0, 0);
        acc[m][n] = __builtin_amdgcn_mfma_f32_16x16x32_bf16(afl[m], bfh[n], acc[m][n], 0, 0, 0);
      }
    __builtin_amdgcn_s_setprio(0);
    __syncthreads();

    if (FUSE) {  // embedded scatter: atomics after kc0, stores after kc1
      if (kc == 0) {
#pragma unroll
        for (int j = 0; j < SJ; ++j)
          epos[j] = (ebuf[j].y >= 0) ? atomicAdd(&wpos[ebuf[j].y], 1) : -1;
      } else if (kc == 1) {
#pragma unroll
        for (int j = 0; j < SJ; ++j)
          if (epos[j] >= 0) csr[epos[j]] = ebuf[j].x;
      }
    }
  }

  __half* __restrict__ C = (by == 0) ? Cl : Cr;
#pragma unroll
  for (int m = 0; m < 4; ++m)
#pragma unroll
    for (int r = 0; r < 4; ++r) {
      int grow = rowBase + rowHalf + m * 16 + quad * 4 + r;
      if (grow < nrows) {
#pragma unroll
        for (int n = 0; n < 4; ++n)
          C[(size_t)grow * 128 + colHalf + n * 16 + l15] = __float2half(acc[m][n][r]);
      }
    }
}

// ------------------------------ attention ----------------------------------
// R10-proven form. One wave per node; 16 lanes/edge (8 ch/lane, one b128
// fp16 load); 4 edge-slots/wave. Main loop 16 edges/iter, tail 4 edges/iter.
// Self loop lives in csr (csr[beg] = node). Outputs fp32 and/or fp16.
__global__ __launch_bounds__(256) void gat_attn(const __half* __restrict__ xl,
                                                const __half* __restrict__ xr,
                                                const int* __restrict__ row_start,
                                                const int* __restrict__ csr,
                                                const float* __restrict__ att,
                                                const float* __restrict__ bias,
                                                float* __restrict__ ofp,
                                                __half* __restrict__ oh16,
                                                int n_nodes) {
  int node = blockIdx.x * 4 + (threadIdx.x >> 6);
  if (node >= n_nodes) return;
  int lane = threadIdx.x & 63;
  int slot = lane >> 4;
  int l15 = lane & 15;
  int c0 = l15 * 8;

  // xr row (fp16 -> fp32)
  float fxr[8];
  {
    uint4 raw = *(const uint4*)&xr[(size_t)node * 128 + c0];
    const __half* hp = (const __half*)&raw;
#pragma unroll
    for (int k = 0; k < 8; ++k) fxr[k] = __half2float(hp[k]);
  }
  // att row, pre-scaled: a06 = 0.6*log2e*a, a04 = 0.4*log2e*a
  float a06[8], a04[8];
  {
    float4 a0 = *(const float4*)&att[c0];
    float4 a1 = *(const float4*)&att[c0 + 4];
    float av[8] = {a0.x, a0.y, a0.z, a0.w, a1.x, a1.y, a1.z, a1.w};
    const float C06 = 0.6f * LOG2E, C04 = 0.4f * LOG2E;
#pragma unroll
    for (int k = 0; k < 8; ++k) { a06[k] = av[k] * C06; a04[k] = av[k] * C04; }
  }

  float acc[8];
#pragma unroll
  for (int k = 0; k < 8; ++k) acc[k] = 0.f;
  float lsum = 0.f;

#define EDGE_BODY(SRC, PVALID)                                                 \
  {                                                                            \
    uint4 raw = *(const uint4*)&xl[(size_t)(unsigned)(SRC)*128 + c0];          \
    const __half* hp = (const __half*)&raw;                                    \
    float e = 0.f;                                                             \
    _Pragma("unroll") for (int k = 0; k < 8; ++k) {                            \
      float t = __half2float(hp[k]) + fxr[k];                                  \
      e = fmaf(a06[k], t, e);                                                  \
      e = fmaf(a04[k], fabsf(t), e);                                           \
    }                                                                          \
    e += __shfl_xor(e, 1);                                                     \
    e += __shfl_xor(e, 2);                                                     \
    float p = (PVALID) ? __builtin_amdgcn_exp2f(e) : 0.f;                      \
    lsum += p;                                                                 \
    _Pragma("unroll") for (int k = 0; k < 8; ++k)                              \
        acc[k] = fmaf(p, __half2float(hp[k]), acc[k]);                         \
  }

  int beg = row_start[node], end = row_start[node + 1];
  int deg = end - beg;  // includes self
  int fullEnd = beg + (deg & ~15);

  for (int base = beg; base < fullEnd; base += 16) {
    int b0 = base + 4 * slot;
    int s0 = csr[b0], s1 = csr[b0 + 1], s2 = csr[b0 + 2], s3 = csr[b0 + 3];
    EDGE_BODY(s0, true);
    EDGE_BODY(s1, true);
    EDGE_BODY(s2, true);
    EDGE_BODY(s3, true);
  }
  for (int base = fullEnd; base < end; base += 4) {  // csr padded by 16
    int idx = base + slot;
    int src = csr[idx];
    EDGE_BODY(src, idx < end);
  }
#undef EDGE_BODY

  // merge the 4 slots (same channels live in lanes with equal l15)
  lsum += __shfl_xor(lsum, 16);
  lsum += __shfl_xor(lsum, 32);
#pragma unroll
  for (int k = 0; k < 8; ++k) {
    acc[k] += __shfl_xor(acc[k], 16);
    acc[k] += __shfl_xor(acc[k], 32);
  }

  if (slot == 0) {
    float4 b0v = *(const float4*)&bias[c0];
    float4 b1v = *(const float4*)&bias[c0 + 4];
    float bv[8] = {b0v.x, b0v.y, b0v.z, b0v.w, b1v.x, b1v.y, b1v.z, b1v.w};
    float inv = 1.f / (lsum + 1e-16f);
    float o[8];
#pragma unroll
    for (int k = 0; k < 8; ++k) {
      float v = fmaf(acc[k], inv, bv[k]);
      o[k] = fmaf(0.495f, fabsf(v), 0.505f * v);  // leaky 0.01
    }
    if (ofp) {
      *(float4*)&ofp[(size_t)node * 128 + c0] = make_float4(o[0], o[1], o[2], o[3]);
      *(float4*)&ofp[(size_t)node * 128 + c0 + 4] = make_float4(o[4], o[5], o[6], o[7]);
    }
    if (oh16) {
      ushort4 ha, hb;
      ha.x = __half_as_ushort(__float2half(o[0]));
      ha.y = __half_as_ushort(__float2half(o[1]));
      ha.z = __half_as_ushort(__float2half(o[2]));
      ha.w = __half_as_ushort(__float2half(o[3]));
      hb.x = __half_as_ushort(__float2half(o[4]));
      hb.y = __half_as_ushort(__float2half(o[5]));
      hb.z = __half_as_ushort(__float2half(o[6]));
      hb.w = __half_as_ushort(__float2half(o[7]));
      *(ushort4*)&oh16[(size_t)node * 128 + c0] = ha;
      *(ushort4*)&oh16[(size_t)node * 128 + c0 + 4] = hb;
    }
  }
}

// ------------------------------ classifier ---------------------------------
__global__ __launch_bounds__(256) void classifier_kernel(const float4* __restrict__ h4,
                                                         const float* __restrict__ Wc,
                                                         const float* __restrict__ bc,
                                                         float* __restrict__ logits,
                                                         int n) {
  __shared__ float sW[2048];
  __shared__ float sb[16];
  int t = threadIdx.x;
#pragma unroll
  for (int i = 0; i < 8; ++i) sW[t + i * 256] = Wc[t + i * 256];
  if (t < 16) sb[t] = bc[t];
  __syncthreads();
  int node = blockIdx.x * 256 + t;
  if (node >= n) return;
  float acc[16];
#pragma unroll
  for (int o = 0; o < 16; ++o) acc[o] = sb[o];
  for (int c4 = 0; c4 < 32; ++c4) {
    float4 hv = h4[(unsigned)node * 32 + c4];
    const float* w = &sW[c4 * 64];
#pragma unroll
    for (int o = 0; o < 16; ++o) {
      acc[o] = fmaf(hv.x, w[o], acc[o]);
      acc[o] = fmaf(hv.y, w[16 + o], acc[o]);
      acc[o] = fmaf(hv.z, w[32 + o], acc[o]);
      acc[o] = fmaf(hv.w, w[48 + o], acc[o]);
    }
  }
#pragma unroll
  for (int q = 0; q < 4; ++q)
    *(float4*)&logits[(size_t)node * 16 + q * 4] =
        make_float4(acc[q * 4], acc[q * 4 + 1], acc[q * 4 + 2], acc[q * 4 + 3]);
}

// ---------------------------------------------------------------------------

extern "C" void kernel_launch(void* const* d_in, const int* in_sizes, int n_in,
                              void* d_out, int out_size, void* d_ws, size_t ws_size,
                              hipStream_t stream) {
  const float* x    = (const float*)d_in[0];
  const int*   ei   = (const int*)d_in[1];
  const float* Wl1  = (const float*)d_in[3];
  const float* Wr1  = (const float*)d_in[4];
  const float* att1 = (const float*)d_in[5];
  const float* b1   = (const float*)d_in[6];
  const float* Wl2  = (const float*)d_in[7];
  const float* Wr2  = (const float*)d_in[8];
  const float* att2 = (const float*)d_in[9];
  const float* b2   = (const float*)d_in[10];
  const float* Wc   = (const float*)d_in[11];
  const float* bc   = (const float*)d_in[12];

  const int N = in_sizes[0] / 128;
  const int E = in_sizes[1] / 2;

  float* outp   = (float*)d_out;
  float* logits = outp;                   // N*16 fp32
  float* hout   = outp + (size_t)N * 16;  // N*128 fp32 region
  // h1 (fp16) staged in the hout region (overwritten by fp32 h2 later)
  __half* h1f16 = (__half*)hout;

  const int cap = E / 8 + 16384;  // per-slice bucket capacity (27+ sigma)

  char* ws = (char*)d_ws;
  __half* xlbuf = (__half*)ws;                ws += (size_t)N * 128 * 2;
  __half* xrbuf = (__half*)ws;                ws += (size_t)N * 128 * 2;
  unsigned short* WT1h = (unsigned short*)ws; ws += 256 * 128 * 2;
  unsigned short* WT1l = (unsigned short*)ws; ws += 256 * 128 * 2;
  unsigned short* WT2h = (unsigned short*)ws; ws += 256 * 128 * 2;
  unsigned short* WT2l = (unsigned short*)ws; ws += 256 * 128 * 2;
  int* cnt       = (int*)ws;                  ws += (size_t)N * 4;
  int* bucketCur = (int*)ws;                  ws += 8 * 4;           // after cnt (one memset)
  int* wpos      = (int*)ws;                  ws += (size_t)N * 4;
  int* bsum      = (int*)ws;                  ws += 256 * 4;
  int2* bucket   = (int2*)ws;                 ws += (size_t)8 * cap * 8;
  int* row_start = (int*)ws;                  ws += (size_t)(N + 1) * 4;
  int* csr       = (int*)ws;                  ws += (size_t)(E + N + 16) * 4;

  const int* esrc = ei;
  const int* edst = ei + E;

  int gN = (N + 255) / 256;
  int gAttn = (N + 3) / 4;
  int sliceSize = (N + 7) / 8;

  int nbx = (N + 127) / 128;
  int nGemm = nbx * 2;
  int gFused = (nGemm + 7) & ~7;  // pad to %8: every slice gets equal blocks

  // CSR build (self loops embedded: counts+1, csr[beg]=node)
  hipMemsetAsync(cnt, 0, (size_t)(N + 8) * 4, stream);  // cnt + bucketCur
  convert_count<<<256 + (E + EPB - 1) / EPB, 256, 0, stream>>>(
      Wl1, Wr1, Wl2, Wr2, WT1h, WT1l, WT2h, WT2l,
      esrc, edst, cnt, bucketCur, bucket, E, sliceSize, cap);
  scan_blk<<<gN, 256, 0, stream>>>(cnt, row_start, bsum, N);
  scan_add<<<gN, 256, 0, stream>>>(row_start, bsum, wpos, csr, N, E + N, gN);

  // layer 1 GEMM (fp32 x, split inline) with embedded bucketed CSR scatter
  gemm_mfma<IN_F32, 1><<<gFused, 256, 0, stream>>>(
      x, nullptr, WT1h, WT1l, xlbuf, xrbuf, N,
      bucket, bucketCur, wpos, csr, cap);
  gat_attn<<<gAttn, 256, 0, stream>>>(xlbuf, xrbuf, row_start, csr, att1, b1,
                                      nullptr, h1f16, N);

  // layer 2 (reads fp16 h1, splits inline; writes fp16 xl/xr)
  gemm_mfma<IN_F16, 0><<<dim3(nbx, 2), 256, 0, stream>>>(
      nullptr, h1f16, WT2h, WT2l, xlbuf, xrbuf, N,
      nullptr, nullptr, nullptr, nullptr, 0);
  gat_attn<<<gAttn, 256, 0, stream>>>(xlbuf, xrbuf, row_start, csr, att2, b2,
                                      hout, nullptr, N);

  // classifier
  classifier_kernel<<<(N + 255) / 256, 256, 0, stream>>>((const float4*)hout, Wc, bc,
                                                         logits, N);
}

// Round 9
// 303.632 us; speedup vs baseline: 1.0503x; 1.0503x over previous
//
#include <hip/hip_runtime.h>
#include <hip/hip_fp16.h>

// ---------------------------------------------------------------------------
// GATv2 x2 + classifier. N=50000, E=800000, IN=128, HEADS=4, HID=32, OUT=16.
// R19: (a) fused gemm1+scatter REVERTED to R17 role-split form (proven 49.3us;
//      R18's intra-block embedding put scatter latency on the barrier-locked
//      MFMA critical path: 64us, occupancy 20.8->15.5%). Role-split fusion is
//      the right structure for heterogeneous work.
//      (b) GEMM switched split-bf16 -> split-fp16: fp32 splits to fp16 hi+lo
//      with 2^-22 residual (vs 2^-16 bf16) and v_cvt_f16_f32 is 1 VALU op vs
//      ~3 for sw-bf16-round. gemm1: same 3 terms, cheaper staging. gemm2:
//      h1 is ALREADY fp16 => A exact, no split, pure uint4 staging, only
//      2 MFMA terms (A*Wh + A*Wl), LDS 40->30KB (5 blocks/CU).
//      (c) scan_bsum stays merged into scan_add (R18, passed).
//      KEPT: bucket pre-partition (FETCH 51->29MB), R10-form attn + separate
//      classifier, h1 fp16, setprio MFMA cluster.
// ---------------------------------------------------------------------------

#define LOG2E 1.4426950408889634f
#define AST 40  // LDS row stride in shorts (80B rows; fragment reads 2-way=free)

typedef _Float16 f16x8 __attribute__((ext_vector_type(8)));
typedef float f32x4 __attribute__((ext_vector_type(4)));

__device__ __forceinline__ unsigned short f2bf(float f) {
  union { float f; unsigned u; } x; x.f = f;
  unsigned r = x.u + 0x7fffu + ((x.u >> 16) & 1u);
  return (unsigned short)(r >> 16);
}
__device__ __forceinline__ float bf2f(unsigned short h) {
  union { unsigned u; float f; } x; x.u = ((unsigned)h) << 16;
  return x.f;
}
// fp16 hi/lo split: v = hi + lo + O(2^-22 * v)
__device__ __forceinline__ void split4h(float4 v, ushort4& h, ushort4& l) {
  __half hx = __float2half(v.x), hy = __float2half(v.y);
  __half hz = __float2half(v.z), hw = __float2half(v.w);
  h.x = __half_as_ushort(hx); l.x = __half_as_ushort(__float2half(v.x - __half2float(hx)));
  h.y = __half_as_ushort(hy); l.y = __half_as_ushort(__float2half(v.y - __half2float(hy)));
  h.z = __half_as_ushort(hz); l.z = __half_as_ushort(__float2half(v.z - __half2float(hz)));
  h.w = __half_as_ushort(hw); l.w = __half_as_ushort(__float2half(v.w - __half2float(hw)));
}

// ------------------------------ CSR build ----------------------------------

// per-block scan of (cnt[i]+1)  (+1 = self loop slot)
__global__ __launch_bounds__(256) void scan_blk(const int* __restrict__ cnt,
                                                int* __restrict__ excl,
                                                int* __restrict__ bsum, int n) {
  __shared__ int s[256];
  int t = threadIdx.x, i = blockIdx.x * 256 + t;
  int v = (i < n) ? (cnt[i] + 1) : 0;
  s[t] = v;
  __syncthreads();
#pragma unroll
  for (int off = 1; off < 256; off <<= 1) {
    int u = (t >= off) ? s[t - off] : 0;
    __syncthreads();
    s[t] += u;
    __syncthreads();
  }
  if (i < n) excl[i] = s[t] - v;
  if (t == 255) bsum[blockIdx.x] = s[255];
}

// merged bsum-scan + add: each block scans bsum[0..nb) in LDS (nb<=256),
// takes its own exclusive prefix; writes row_start/wpos/self-loop; block 0
// also writes row_start[n] (total) and zeroes the csr pad.
__global__ __launch_bounds__(256) void scan_add(int* __restrict__ row_start,
                                                const int* __restrict__ bsum,
                                                int* __restrict__ wpos,
                                                int* __restrict__ csr,
                                                int n, int padBase, int nb) {
  __shared__ int s[256];
  int t = threadIdx.x;
  int v = (t < nb) ? bsum[t] : 0;
  s[t] = v;
  __syncthreads();
#pragma unroll
  for (int off = 1; off < 256; off <<= 1) {
    int u = (t >= off) ? s[t - off] : 0;
    __syncthreads();
    s[t] += u;
    __syncthreads();
  }
  int pref = (blockIdx.x > 0) ? s[blockIdx.x - 1] : 0;
  int i = blockIdx.x * 256 + t;
  if (i < n) {
    int r = row_start[i] + pref;
    row_start[i] = r;
    wpos[i] = r + 1;
    csr[r] = i;  // self loop first in each row
  }
  if (blockIdx.x == 0) {
    if (t == 0) row_start[n] = s[nb - 1];
    if (t < 16) csr[padBase + t] = 0;
  }
}

// ------------- weight convert + degree count + slice bucketing -------------
// blocks 0..255: split-fp16 weight transpose (both layers)
// blocks 256.. : 1024 edges each: degree count + append (src,dst) to the
//                dst-slice bucket (LDS histogram -> 1 global cursor
//                atomicAdd per bucket -> contiguous run writes).
#define EPB 1024
__global__ __launch_bounds__(256) void convert_count(
    const float* __restrict__ Wl1, const float* __restrict__ Wr1,
    const float* __restrict__ Wl2, const float* __restrict__ Wr2,
    unsigned short* __restrict__ BT1h, unsigned short* __restrict__ BT1l,
    unsigned short* __restrict__ BT2h, unsigned short* __restrict__ BT2l,
    const int* __restrict__ esrc, const int* __restrict__ edst,
    int* __restrict__ cnt, int* __restrict__ bucketCur,
    int2* __restrict__ bucket, int E, int sliceSize, int cap) {
  int b = blockIdx.x;
  int t = threadIdx.x;
  if (b >= 256) {
    __shared__ int bcnt[8], bbase[8];
    if (t < 8) bcnt[t] = 0;
    __syncthreads();
    int base = (b - 256) * EPB;
    int sl[4], rk[4], dv[4], sv[4];
#pragma unroll
    for (int j = 0; j < 4; ++j) {
      int i = base + t + j * 256;
      bool v = (i < E);
      int d = v ? edst[i] : 0;
      sv[j] = v ? esrc[i] : 0;
      dv[j] = d;
      int s = d / sliceSize;  // 0..7
      sl[j] = v ? s : -1;
      if (v) {
        atomicAdd(&cnt[d], 1);
        rk[j] = atomicAdd(&bcnt[s], 1);
      }
    }
    __syncthreads();
    if (t < 8 && bcnt[t] > 0) bbase[t] = atomicAdd(&bucketCur[t], bcnt[t]);
    __syncthreads();
#pragma unroll
    for (int j = 0; j < 4; ++j) {
      if (sl[j] >= 0) {
        int pos = sl[j] * cap + bbase[sl[j]] + rk[j];
        bucket[pos] = make_int2(sv[j], dv[j]);
      }
    }
    return;
  }
  const float* Wl = (b < 128) ? Wl1 : Wl2;
  const float* Wr = (b < 128) ? Wr1 : Wr2;
  unsigned short* BTh = (b < 128) ? BT1h : BT2h;
  unsigned short* BTl = (b < 128) ? BT1l : BT2l;
  int idx = (b & 127) * 256 + t;  // 0..32767
  int col = idx >> 7, k = idx & 127;
  float v = (col < 128) ? Wl[k * 128 + col] : Wr[k * 128 + (col - 128)];
  __half h = __float2half(v);
  BTh[idx] = __half_as_ushort(h);
  BTl[idx] = __half_as_ushort(__float2half(v - __half2float(h)));
}

// ------------------------ MFMA GEMM (+fused scatter) -----------------------
// C[N x 256] = A[N x 128] @ W[128 x 256], split-fp16; C stored fp16.
// IN_F32: A split to fp16 hi/lo (residual 2^-22), 3 MFMA terms, 40KB LDS.
// IN_F16: A exact fp16 (no split, pure copies), 2 MFMA terms, 30KB LDS.
// Block = 128 rows x 128 cols. 4 waves, each 64x64 (16 acc tiles).
// FUSE=1: grid also carries scatter blocks (5 of every 9). Scatter slice is
// the REAL blockIdx&7 (== XCD on round-robin dispatch) so each csr slice is
// written by exactly one XCD's L2; chunk = rank among same-slice blocks.
// Scatter reads ONLY its slice's pre-bucketed edges (1x scan, no filter).
enum { IN_F32 = 0, IN_F16 = 1 };
#define NSCAT 1152
#define NCHUNK 128
template <int MODE, int FUSE>
__global__ __launch_bounds__(256) void gemm_mfma(
    const float* __restrict__ Af, const __half* __restrict__ Af16,
    const unsigned short* __restrict__ BTh, const unsigned short* __restrict__ BTl,
    __half* __restrict__ Cl, __half* __restrict__ Cr, int nrows,
    const int2* __restrict__ bucket, const int* __restrict__ bucketCur,
    int* __restrict__ wpos, int* __restrict__ csr, int cap) {
  constexpr int NBUF = (MODE == IN_F16) ? 3 : 4;
  __shared__ __align__(16) unsigned short smem[NBUF * 128 * AST];
  int tid = threadIdx.x;
  int bx, by;
  if (FUSE) {
    int g = blockIdx.x / 9, r = blockIdx.x - g * 9;
    if (r < 5) {  // ---- scatter role ----
      int sid = g * 5 + r;
      if (sid < NSCAT) {
        int slice = blockIdx.x & 7;  // == XCD (round-robin dispatch)
        // rank among scatter blocks with the same slice, ordered by g:
        // block (g',r') has slice (g'+r')&7; per g' at most one r'<5 matches.
        int chunk = (g >> 3) * 5;
        for (int gp = g & ~7; gp < g; ++gp)
          chunk += (((slice - gp) & 7) < 5) ? 1 : 0;
        if (chunk < NCHUNK) {
          int cntS = bucketCur[slice];
          int per = (cntS + NCHUNK - 1) / NCHUNK;
          int b0 = chunk * per;
          int ee = min(b0 + per, cntS);
          const int2* bk = bucket + (size_t)slice * cap;
          int i = b0 + tid;
          // 2x-batched: 2 independent bucket loads in flight
          for (; i + 256 < ee; i += 512) {
            int2 e0 = bk[i];
            int2 e1 = bk[i + 256];
            int p0 = atomicAdd(&wpos[e0.y], 1); csr[p0] = e0.x;
            int p1 = atomicAdd(&wpos[e1.y], 1); csr[p1] = e1.x;
          }
          for (; i < ee; i += 256) {
            int2 e = bk[i];
            int p = atomicAdd(&wpos[e.y], 1); csr[p] = e.x;
          }
        }
      }
      return;
    }
    int gid = g * 4 + (r - 5);  // ---- gemm role ----
    int nbx = (nrows + 127) >> 7;
    if (gid >= nbx * 2) return;
    bx = gid >> 1;
    by = gid & 1;
  } else {
    bx = blockIdx.x;
    by = blockIdx.y;
  }

  constexpr int ABUF = 128 * AST;  // 5120 shorts
  unsigned short* sAh = smem;
  unsigned short* sAl = (MODE == IN_F32) ? smem + ABUF : nullptr;
  unsigned short* sBh = smem + ((MODE == IN_F32) ? 2 * ABUF : ABUF);
  unsigned short* sBl = smem + ((MODE == IN_F32) ? 3 * ABUF : 2 * ABUF);

  int wave = tid >> 6, lane = tid & 63;
  int rowBase = bx * 128;
  int colBase = by * 128;
  int rowHalf = (wave >> 1) * 64;
  int colHalf = (wave & 1) * 64;
  int l15 = lane & 15, quad = lane >> 4;

  f32x4 acc[4][4];
#pragma unroll
  for (int m = 0; m < 4; ++m)
#pragma unroll
    for (int n = 0; n < 4; ++n) acc[m][n] = (f32x4){0.f, 0.f, 0.f, 0.f};

  for (int kc = 0; kc < 4; ++kc) {
    // stage A: 128 rows x 32 k; idx 0..511, 8 k-elems each
#pragma unroll
    for (int i = 0; i < 2; ++i) {
      int idx = tid + i * 256;
      int row = idx >> 2, seg = idx & 3;
      int gr = rowBase + row;
      if (MODE == IN_F32) {
        float4 v0 = make_float4(0.f, 0.f, 0.f, 0.f), v1 = v0;
        if (gr < nrows) {
          v0 = *(const float4*)&Af[(size_t)gr * 128 + kc * 32 + seg * 8];
          v1 = *(const float4*)&Af[(size_t)gr * 128 + kc * 32 + seg * 8 + 4];
        }
        ushort4 h0, l0, h1, l1;
        split4h(v0, h0, l0);
        split4h(v1, h1, l1);
        *(ushort4*)&sAh[row * AST + seg * 8] = h0;
        *(ushort4*)&sAh[row * AST + seg * 8 + 4] = h1;
        *(ushort4*)&sAl[row * AST + seg * 8] = l0;
        *(ushort4*)&sAl[row * AST + seg * 8 + 4] = l1;
      } else {  // h1 is already fp16: exact A operand, pure copy
        uint4 raw = make_uint4(0, 0, 0, 0);
        if (gr < nrows)
          raw = *(const uint4*)&Af16[(size_t)gr * 128 + kc * 32 + seg * 8];
        *(uint4*)&sAh[row * AST + seg * 8] = raw;
      }
    }
    // stage B: 128 cols x 32 k (hi+lo); idx 0..511
#pragma unroll
    for (int i = 0; i < 2; ++i) {
      int idx = tid + i * 256;
      int col = idx >> 2, seg = idx & 3;
      *(uint4*)&sBh[col * AST + seg * 8] =
          *(const uint4*)&BTh[(size_t)(colBase + col) * 128 + kc * 32 + seg * 8];
      *(uint4*)&sBl[col * AST + seg * 8] =
          *(const uint4*)&BTl[(size_t)(colBase + col) * 128 + kc * 32 + seg * 8];
    }
    __syncthreads();

    f16x8 afh[4], afl[4], bfh[4], bfl[4];
#pragma unroll
    for (int m = 0; m < 4; ++m) {
      int r = rowHalf + m * 16 + l15;
      afh[m] = *(const f16x8*)&sAh[r * AST + quad * 8];
      if (MODE == IN_F32) afl[m] = *(const f16x8*)&sAl[r * AST + quad * 8];
    }
#pragma unroll
    for (int n = 0; n < 4; ++n) {
      int cc = colHalf + n * 16 + l15;
      bfh[n] = *(const f16x8*)&sBh[cc * AST + quad * 8];
      bfl[n] = *(const f16x8*)&sBl[cc * AST + quad * 8];
    }
    __builtin_amdgcn_s_setprio(1);
#pragma unroll
    for (int m = 0; m < 4; ++m)
#pragma unroll
      for (int n = 0; n < 4; ++n) {
        acc[m][n] = __builtin_amdgcn_mfma_f32_16x16x32_f16(afh[m], bfh[n], acc[m][n], 0, 0, 0);
        acc[m][n] = __builtin_amdgcn_mfma_f32_16x16x32_f16(afh[m], bfl[n], acc[m][n], 0, 0, 0);
        if (MODE == IN_F32)
          acc[m][n] = __builtin_amdgcn_mfma_f32_16x16x32_f16(afl[m], bfh[n], acc[m][n], 0, 0, 0);
      }
    __builtin_amdgcn_s_setprio(0);
    __syncthreads();
  }

  __half* __restrict__ C = (by == 0) ? Cl : Cr;
#pragma unroll
  for (int m = 0; m < 4; ++m)
#pragma unroll
    for (int r = 0; r < 4; ++r) {
      int grow = rowBase + rowHalf + m * 16 + quad * 4 + r;
      if (grow < nrows) {
#pragma unroll
        for (int n = 0; n < 4; ++n)
          C[(size_t)grow * 128 + colHalf + n * 16 + l15] = __float2half(acc[m][n][r]);
      }
    }
}

// ------------------------------ attention ----------------------------------
// R10-proven form. One wave per node; 16 lanes/edge (8 ch/lane, one b128
// fp16 load); 4 edge-slots/wave. Main loop 16 edges/iter, tail 4 edges/iter.
// Self loop lives in csr (csr[beg] = node). Outputs fp32 and/or fp16.
__global__ __launch_bounds__(256) void gat_attn(const __half* __restrict__ xl,
                                                const __half* __restrict__ xr,
                                                const int* __restrict__ row_start,
                                                const int* __restrict__ csr,
                                                const float* __restrict__ att,
                                                const float* __restrict__ bias,
                                                float* __restrict__ ofp,
                                                __half* __restrict__ oh16,
                                                int n_nodes) {
  int node = blockIdx.x * 4 + (threadIdx.x >> 6);
  if (node >= n_nodes) return;
  int lane = threadIdx.x & 63;
  int slot = lane >> 4;
  int l15 = lane & 15;
  int c0 = l15 * 8;

  // xr row (fp16 -> fp32)
  float fxr[8];
  {
    uint4 raw = *(const uint4*)&xr[(size_t)node * 128 + c0];
    const __half* hp = (const __half*)&raw;
#pragma unroll
    for (int k = 0; k < 8; ++k) fxr[k] = __half2float(hp[k]);
  }
  // att row, pre-scaled: a06 = 0.6*log2e*a, a04 = 0.4*log2e*a
  float a06[8], a04[8];
  {
    float4 a0 = *(const float4*)&att[c0];
    float4 a1 = *(const float4*)&att[c0 + 4];
    float av[8] = {a0.x, a0.y, a0.z, a0.w, a1.x, a1.y, a1.z, a1.w};
    const float C06 = 0.6f * LOG2E, C04 = 0.4f * LOG2E;
#pragma unroll
    for (int k = 0; k < 8; ++k) { a06[k] = av[k] * C06; a04[k] = av[k] * C04; }
  }

  float acc[8];
#pragma unroll
  for (int k = 0; k < 8; ++k) acc[k] = 0.f;
  float lsum = 0.f;

#define EDGE_BODY(SRC, PVALID)                                                 \
  {                                                                            \
    uint4 raw = *(const uint4*)&xl[(size_t)(unsigned)(SRC)*128 + c0];          \
    const __half* hp = (const __half*)&raw;                                    \
    float e = 0.f;                                                             \
    _Pragma("unroll") for (int k = 0; k < 8; ++k) {                            \
      float t = __half2float(hp[k]) + fxr[k];                                  \
      e = fmaf(a06[k], t, e);                                                  \
      e = fmaf(a04[k], fabsf(t), e);                                           \
    }                                                                          \
    e += __shfl_xor(e, 1);                                                     \
    e += __shfl_xor(e, 2);                                                     \
    float p = (PVALID) ? __builtin_amdgcn_exp2f(e) : 0.f;                      \
    lsum += p;                                                                 \
    _Pragma("unroll") for (int k = 0; k < 8; ++k)                              \
        acc[k] = fmaf(p, __half2float(hp[k]), acc[k]);                         \
  }

  int beg = row_start[node], end = row_start[node + 1];
  int deg = end - beg;  // includes self
  int fullEnd = beg + (deg & ~15);

  for (int base = beg; base < fullEnd; base += 16) {
    int b0 = base + 4 * slot;
    int s0 = csr[b0], s1 = csr[b0 + 1], s2 = csr[b0 + 2], s3 = csr[b0 + 3];
    EDGE_BODY(s0, true);
    EDGE_BODY(s1, true);
    EDGE_BODY(s2, true);
    EDGE_BODY(s3, true);
  }
  for (int base = fullEnd; base < end; base += 4) {  // csr padded by 16
    int idx = base + slot;
    int src = csr[idx];
    EDGE_BODY(src, idx < end);
  }
#undef EDGE_BODY

  // merge the 4 slots (same channels live in lanes with equal l15)
  lsum += __shfl_xor(lsum, 16);
  lsum += __shfl_xor(lsum, 32);
#pragma unroll
  for (int k = 0; k < 8; ++k) {
    acc[k] += __shfl_xor(acc[k], 16);
    acc[k] += __shfl_xor(acc[k], 32);
  }

  if (slot == 0) {
    float4 b0v = *(const float4*)&bias[c0];
    float4 b1v = *(const float4*)&bias[c0 + 4];
    float bv[8] = {b0v.x, b0v.y, b0v.z, b0v.w, b1v.x, b1v.y, b1v.z, b1v.w};
    float inv = 1.f / (lsum + 1e-16f);
    float o[8];
#pragma unroll
    for (int k = 0; k < 8; ++k) {
      float v = fmaf(acc[k], inv, bv[k]);
      o[k] = fmaf(0.495f, fabsf(v), 0.505f * v);  // leaky 0.01
    }
    if (ofp) {
      *(float4*)&ofp[(size_t)node * 128 + c0] = make_float4(o[0], o[1], o[2], o[3]);
      *(float4*)&ofp[(size_t)node * 128 + c0 + 4] = make_float4(o[4], o[5], o[6], o[7]);
    }
    if (oh16) {
      ushort4 ha, hb;
      ha.x = __half_as_ushort(__float2half(o[0]));
      ha.y = __half_as_ushort(__float2half(o[1]));
      ha.z = __half_as_ushort(__float2half(o[2]));
      ha.w = __half_as_ushort(__float2half(o[3]));
      hb.x = __half_as_ushort(__float2half(o[4]));
      hb.y = __half_as_ushort(__float2half(o[5]));
      hb.z = __half_as_ushort(__float2half(o[6]));
      hb.w = __half_as_ushort(__float2half(o[7]));
      *(ushort4*)&oh16[(size_t)node * 128 + c0] = ha;
      *(ushort4*)&oh16[(size_t)node * 128 + c0 + 4] = hb;
    }
  }
}

// ------------------------------ classifier ---------------------------------
__global__ __launch_bounds__(256) void classifier_kernel(const float4* __restrict__ h4,
                                                         const float* __restrict__ Wc,
                                                         const float* __restrict__ bc,
                                                         float* __restrict__ logits,
                                                         int n) {
  __shared__ float sW[2048];
  __shared__ float sb[16];
  int t = threadIdx.x;
#pragma unroll
  for (int i = 0; i < 8; ++i) sW[t + i * 256] = Wc[t + i * 256];
  if (t < 16) sb[t] = bc[t];
  __syncthreads();
  int node = blockIdx.x * 256 + t;
  if (node >= n) return;
  float acc[16];
#pragma unroll
  for (int o = 0; o < 16; ++o) acc[o] = sb[o];
  for (int c4 = 0; c4 < 32; ++c4) {
    float4 hv = h4[(unsigned)node * 32 + c4];
    const float* w = &sW[c4 * 64];
#pragma unroll
    for (int o = 0; o < 16; ++o) {
      acc[o] = fmaf(hv.x, w[o], acc[o]);
      acc[o] = fmaf(hv.y, w[16 + o], acc[o]);
      acc[o] = fmaf(hv.z, w[32 + o], acc[o]);
      acc[o] = fmaf(hv.w, w[48 + o], acc[o]);
    }
  }
#pragma unroll
  for (int q = 0; q < 4; ++q)
    *(float4*)&logits[(size_t)node * 16 + q * 4] =
        make_float4(acc[q * 4], acc[q * 4 + 1], acc[q * 4 + 2], acc[q * 4 + 3]);
}

// ---------------------------------------------------------------------------

extern "C" void kernel_launch(void* const* d_in, const int* in_sizes, int n_in,
                              void* d_out, int out_size, void* d_ws, size_t ws_size,
                              hipStream_t stream) {
  const float* x    = (const float*)d_in[0];
  const int*   ei   = (const int*)d_in[1];
  const float* Wl1  = (const float*)d_in[3];
  const float* Wr1  = (const float*)d_in[4];
  const float* att1 = (const float*)d_in[5];
  const float* b1   = (const float*)d_in[6];
  const float* Wl2  = (const float*)d_in[7];
  const float* Wr2  = (const float*)d_in[8];
  const float* att2 = (const float*)d_in[9];
  const float* b2   = (const float*)d_in[10];
  const float* Wc   = (const float*)d_in[11];
  const float* bc   = (const float*)d_in[12];

  const int N = in_sizes[0] / 128;
  const int E = in_sizes[1] / 2;

  float* outp   = (float*)d_out;
  float* logits = outp;                   // N*16 fp32
  float* hout   = outp + (size_t)N * 16;  // N*128 fp32 region
  // h1 (fp16) staged in the hout region (overwritten by fp32 h2 later)
  __half* h1f16 = (__half*)hout;

  const int cap = E / 8 + 16384;  // per-slice bucket capacity (27+ sigma)

  char* ws = (char*)d_ws;
  __half* xlbuf = (__half*)ws;                ws += (size_t)N * 128 * 2;
  __half* xrbuf = (__half*)ws;                ws += (size_t)N * 128 * 2;
  unsigned short* WT1h = (unsigned short*)ws; ws += 256 * 128 * 2;
  unsigned short* WT1l = (unsigned short*)ws; ws += 256 * 128 * 2;
  unsigned short* WT2h = (unsigned short*)ws; ws += 256 * 128 * 2;
  unsigned short* WT2l = (unsigned short*)ws; ws += 256 * 128 * 2;
  int* cnt       = (int*)ws;                  ws += (size_t)N * 4;
  int* bucketCur = (int*)ws;                  ws += 8 * 4;           // after cnt (one memset)
  int* wpos      = (int*)ws;                  ws += (size_t)N * 4;
  int* bsum      = (int*)ws;                  ws += 256 * 4;
  int2* bucket   = (int2*)ws;                 ws += (size_t)8 * cap * 8;
  int* row_start = (int*)ws;                  ws += (size_t)(N + 1) * 4;
  int* csr       = (int*)ws;                  ws += (size_t)(E + N + 16) * 4;

  const int* esrc = ei;
  const int* edst = ei + E;

  int gN = (N + 255) / 256;
  int gAttn = (N + 3) / 4;
  int sliceSize = (N + 7) / 8;

  int nbx = (N + 127) / 128;
  int nGemm = nbx * 2;
  int groups = (NSCAT + 4) / 5;  // 231 -> covers >=128 chunks per slice
  int g2 = (nGemm + 3) / 4;
  if (g2 > groups) groups = g2;
  int gFused = groups * 9;

  // CSR build (self loops embedded: counts+1, csr[beg]=node)
  hipMemsetAsync(cnt, 0, (size_t)(N + 8) * 4, stream);  // cnt + bucketCur
  convert_count<<<256 + (E + EPB - 1) / EPB, 256, 0, stream>>>(
      Wl1, Wr1, Wl2, Wr2, WT1h, WT1l, WT2h, WT2l,
      esrc, edst, cnt, bucketCur, bucket, E, sliceSize, cap);
  scan_blk<<<gN, 256, 0, stream>>>(cnt, row_start, bsum, N);
  scan_add<<<gN, 256, 0, stream>>>(row_start, bsum, wpos, csr, N, E + N, gN);

  // layer 1 GEMM (fp32 x, fp16-split inline) fused with bucketed CSR scatter
  gemm_mfma<IN_F32, 1><<<gFused, 256, 0, stream>>>(
      x, nullptr, WT1h, WT1l, xlbuf, xrbuf, N,
      bucket, bucketCur, wpos, csr, cap);
  gat_attn<<<gAttn, 256, 0, stream>>>(xlbuf, xrbuf, row_start, csr, att1, b1,
                                      nullptr, h1f16, N);

  // layer 2 (h1 fp16 = exact A operand: no split, 2-term, 30KB LDS)
  gemm_mfma<IN_F16, 0><<<dim3(nbx, 2), 256, 0, stream>>>(
      nullptr, h1f16, WT2h, WT2l, xlbuf, xrbuf, N,
      nullptr, nullptr, nullptr, nullptr, 0);
  gat_attn<<<gAttn, 256, 0, stream>>>(xlbuf, xrbuf, row_start, csr, att2, b2,
                                      hout, nullptr, N);

  // classifier
  classifier_kernel<<<(N + 255) / 256, 256, 0, stream>>>((const float4*)hout, Wc, bc,
                                                         logits, N);
}

// Round 10
// 303.611 us; speedup vs baseline: 1.0503x; 1.0001x over previous
//
#include <hip/hip_runtime.h>
#include <hip/hip_fp16.h>

// ---------------------------------------------------------------------------
// GATv2 x2 + classifier. N=50000, E=800000, IN=128, HEADS=4, HID=32, OUT=16.
// R20: LDS-staged coalesced C epilogue in both gemms. Counters (all rounds):
//      fused WRITE 56.7MB vs logical 29MB -- exactly 2x on the xl/xr store.
//      Old epilogue wrote 32B partial rows per instruction (cols n*16+l15,
//      2B/lane) -> every 256B C-line filled by 8 scattered chunks -> 2x HBM
//      write amplification. Now: stage the 128x128 fp16 C-tile in the (dead
//      after last barrier) smem, then store 16-lanes-per-row = 4 full 256B
//      rows per instruction. Stride 132 (gemm1, conflict-free in 40KB) /
//      128 (gemm2, keeps 32KB -> 5 blocks/CU). Bit-identical values.
//      KEPT (verified): R17 role-split fused scatter+gemm1 (slice<->XCD),
//      fp16-split GEMM (R19: gemm2 2-term/no-split), bucket pre-partition,
//      merged scans, R10-form attn + separate classifier, h1 fp16, setprio.
// ---------------------------------------------------------------------------

#define LOG2E 1.4426950408889634f
#define AST 40  // LDS row stride in shorts (80B rows; fragment reads 2-way=free)

typedef _Float16 f16x8 __attribute__((ext_vector_type(8)));
typedef float f32x4 __attribute__((ext_vector_type(4)));

__device__ __forceinline__ unsigned short f2bf(float f) {
  union { float f; unsigned u; } x; x.f = f;
  unsigned r = x.u + 0x7fffu + ((x.u >> 16) & 1u);
  return (unsigned short)(r >> 16);
}
__device__ __forceinline__ float bf2f(unsigned short h) {
  union { unsigned u; float f; } x; x.u = ((unsigned)h) << 16;
  return x.f;
}
// fp16 hi/lo split: v = hi + lo + O(2^-22 * v)
__device__ __forceinline__ void split4h(float4 v, ushort4& h, ushort4& l) {
  __half hx = __float2half(v.x), hy = __float2half(v.y);
  __half hz = __float2half(v.z), hw = __float2half(v.w);
  h.x = __half_as_ushort(hx); l.x = __half_as_ushort(__float2half(v.x - __half2float(hx)));
  h.y = __half_as_ushort(hy); l.y = __half_as_ushort(__float2half(v.y - __half2float(hy)));
  h.z = __half_as_ushort(hz); l.z = __half_as_ushort(__float2half(v.z - __half2float(hz)));
  h.w = __half_as_ushort(hw); l.w = __half_as_ushort(__float2half(v.w - __half2float(hw)));
}

// ------------------------------ CSR build ----------------------------------

// per-block scan of (cnt[i]+1)  (+1 = self loop slot)
__global__ __launch_bounds__(256) void scan_blk(const int* __restrict__ cnt,
                                                int* __restrict__ excl,
                                                int* __restrict__ bsum, int n) {
  __shared__ int s[256];
  int t = threadIdx.x, i = blockIdx.x * 256 + t;
  int v = (i < n) ? (cnt[i] + 1) : 0;
  s[t] = v;
  __syncthreads();
#pragma unroll
  for (int off = 1; off < 256; off <<= 1) {
    int u = (t >= off) ? s[t - off] : 0;
    __syncthreads();
    s[t] += u;
    __syncthreads();
  }
  if (i < n) excl[i] = s[t] - v;
  if (t == 255) bsum[blockIdx.x] = s[255];
}

// merged bsum-scan + add: each block scans bsum[0..nb) in LDS (nb<=256),
// takes its own exclusive prefix; writes row_start/wpos/self-loop; block 0
// also writes row_start[n] (total) and zeroes the csr pad.
__global__ __launch_bounds__(256) void scan_add(int* __restrict__ row_start,
                                                const int* __restrict__ bsum,
                                                int* __restrict__ wpos,
                                                int* __restrict__ csr,
                                                int n, int padBase, int nb) {
  __shared__ int s[256];
  int t = threadIdx.x;
  int v = (t < nb) ? bsum[t] : 0;
  s[t] = v;
  __syncthreads();
#pragma unroll
  for (int off = 1; off < 256; off <<= 1) {
    int u = (t >= off) ? s[t - off] : 0;
    __syncthreads();
    s[t] += u;
    __syncthreads();
  }
  int pref = (blockIdx.x > 0) ? s[blockIdx.x - 1] : 0;
  int i = blockIdx.x * 256 + t;
  if (i < n) {
    int r = row_start[i] + pref;
    row_start[i] = r;
    wpos[i] = r + 1;
    csr[r] = i;  // self loop first in each row
  }
  if (blockIdx.x == 0) {
    if (t == 0) row_start[n] = s[nb - 1];
    if (t < 16) csr[padBase + t] = 0;
  }
}

// ------------- weight convert + degree count + slice bucketing -------------
// blocks 0..255: split-fp16 weight transpose (both layers)
// blocks 256.. : 1024 edges each: degree count + append (src,dst) to the
//                dst-slice bucket (LDS histogram -> 1 global cursor
//                atomicAdd per bucket -> contiguous run writes).
#define EPB 1024
__global__ __launch_bounds__(256) void convert_count(
    const float* __restrict__ Wl1, const float* __restrict__ Wr1,
    const float* __restrict__ Wl2, const float* __restrict__ Wr2,
    unsigned short* __restrict__ BT1h, unsigned short* __restrict__ BT1l,
    unsigned short* __restrict__ BT2h, unsigned short* __restrict__ BT2l,
    const int* __restrict__ esrc, const int* __restrict__ edst,
    int* __restrict__ cnt, int* __restrict__ bucketCur,
    int2* __restrict__ bucket, int E, int sliceSize, int cap) {
  int b = blockIdx.x;
  int t = threadIdx.x;
  if (b >= 256) {
    __shared__ int bcnt[8], bbase[8];
    if (t < 8) bcnt[t] = 0;
    __syncthreads();
    int base = (b - 256) * EPB;
    int sl[4], rk[4], dv[4], sv[4];
#pragma unroll
    for (int j = 0; j < 4; ++j) {
      int i = base + t + j * 256;
      bool v = (i < E);
      int d = v ? edst[i] : 0;
      sv[j] = v ? esrc[i] : 0;
      dv[j] = d;
      int s = d / sliceSize;  // 0..7
      sl[j] = v ? s : -1;
      if (v) {
        atomicAdd(&cnt[d], 1);
        rk[j] = atomicAdd(&bcnt[s], 1);
      }
    }
    __syncthreads();
    if (t < 8 && bcnt[t] > 0) bbase[t] = atomicAdd(&bucketCur[t], bcnt[t]);
    __syncthreads();
#pragma unroll
    for (int j = 0; j < 4; ++j) {
      if (sl[j] >= 0) {
        int pos = sl[j] * cap + bbase[sl[j]] + rk[j];
        bucket[pos] = make_int2(sv[j], dv[j]);
      }
    }
    return;
  }
  const float* Wl = (b < 128) ? Wl1 : Wl2;
  const float* Wr = (b < 128) ? Wr1 : Wr2;
  unsigned short* BTh = (b < 128) ? BT1h : BT2h;
  unsigned short* BTl = (b < 128) ? BT1l : BT2l;
  int idx = (b & 127) * 256 + t;  // 0..32767
  int col = idx >> 7, k = idx & 127;
  float v = (col < 128) ? Wl[k * 128 + col] : Wr[k * 128 + (col - 128)];
  __half h = __float2half(v);
  BTh[idx] = __half_as_ushort(h);
  BTl[idx] = __half_as_ushort(__float2half(v - __half2float(h)));
}

// ------------------------ MFMA GEMM (+fused scatter) -----------------------
// C[N x 256] = A[N x 128] @ W[128 x 256], split-fp16; C stored fp16.
// IN_F32: A split to fp16 hi/lo (residual 2^-22), 3 MFMA terms, 40KB LDS.
// IN_F16: A exact fp16 (no split, pure copies), 2 MFMA terms, 32KB LDS.
// Block = 128 rows x 128 cols. 4 waves, each 64x64 (16 acc tiles).
// Epilogue: C-tile staged fp16 in (dead) smem, stored 4 full 256B rows per
// instruction (16 lanes/row) -- kills the 2x partial-line write amplification.
// FUSE=1: grid also carries scatter blocks (5 of every 9). Scatter slice is
// the REAL blockIdx&7 (== XCD on round-robin dispatch) so each csr slice is
// written by exactly one XCD's L2; chunk = rank among same-slice blocks.
enum { IN_F32 = 0, IN_F16 = 1 };
#define NSCAT 1152
#define NCHUNK 128
template <int MODE, int FUSE>
__global__ __launch_bounds__(256) void gemm_mfma(
    const float* __restrict__ Af, const __half* __restrict__ Af16,
    const unsigned short* __restrict__ BTh, const unsigned short* __restrict__ BTl,
    __half* __restrict__ Cl, __half* __restrict__ Cr, int nrows,
    const int2* __restrict__ bucket, const int* __restrict__ bucketCur,
    int* __restrict__ wpos, int* __restrict__ csr, int cap) {
  constexpr int NBUF = (MODE == IN_F16) ? 3 : 4;
  constexpr int CST = (MODE == IN_F32) ? 132 : 128;  // C-tile row stride
  constexpr int SMEMN = (NBUF * 128 * AST > 128 * CST) ? NBUF * 128 * AST
                                                       : 128 * CST;
  __shared__ __align__(16) unsigned short smem[SMEMN];
  int tid = threadIdx.x;
  int bx, by;
  if (FUSE) {
    int g = blockIdx.x / 9, r = blockIdx.x - g * 9;
    if (r < 5) {  // ---- scatter role ----
      int sid = g * 5 + r;
      if (sid < NSCAT) {
        int slice = blockIdx.x & 7;  // == XCD (round-robin dispatch)
        // rank among scatter blocks with the same slice, ordered by g:
        // block (g',r') has slice (g'+r')&7; per g' at most one r'<5 matches.
        int chunk = (g >> 3) * 5;
        for (int gp = g & ~7; gp < g; ++gp)
          chunk += (((slice - gp) & 7) < 5) ? 1 : 0;
        if (chunk < NCHUNK) {
          int cntS = bucketCur[slice];
          int per = (cntS + NCHUNK - 1) / NCHUNK;
          int b0 = chunk * per;
          int ee = min(b0 + per, cntS);
          const int2* bk = bucket + (size_t)slice * cap;
          int i = b0 + tid;
          // 2x-batched: 2 independent bucket loads in flight
          for (; i + 256 < ee; i += 512) {
            int2 e0 = bk[i];
            int2 e1 = bk[i + 256];
            int p0 = atomicAdd(&wpos[e0.y], 1); csr[p0] = e0.x;
            int p1 = atomicAdd(&wpos[e1.y], 1); csr[p1] = e1.x;
          }
          for (; i < ee; i += 256) {
            int2 e = bk[i];
            int p = atomicAdd(&wpos[e.y], 1); csr[p] = e.x;
          }
        }
      }
      return;
    }
    int gid = g * 4 + (r - 5);  // ---- gemm role ----
    int nbx = (nrows + 127) >> 7;
    if (gid >= nbx * 2) return;
    bx = gid >> 1;
    by = gid & 1;
  } else {
    bx = blockIdx.x;
    by = blockIdx.y;
  }

  constexpr int ABUF = 128 * AST;  // 5120 shorts
  unsigned short* sAh = smem;
  unsigned short* sAl = (MODE == IN_F32) ? smem + ABUF : nullptr;
  unsigned short* sBh = smem + ((MODE == IN_F32) ? 2 * ABUF : ABUF);
  unsigned short* sBl = smem + ((MODE == IN_F32) ? 3 * ABUF : 2 * ABUF);

  int wave = tid >> 6, lane = tid & 63;
  int rowBase = bx * 128;
  int colBase = by * 128;
  int rowHalf = (wave >> 1) * 64;
  int colHalf = (wave & 1) * 64;
  int l15 = lane & 15, quad = lane >> 4;

  f32x4 acc[4][4];
#pragma unroll
  for (int m = 0; m < 4; ++m)
#pragma unroll
    for (int n = 0; n < 4; ++n) acc[m][n] = (f32x4){0.f, 0.f, 0.f, 0.f};

  for (int kc = 0; kc < 4; ++kc) {
    // stage A: 128 rows x 32 k; idx 0..511, 8 k-elems each
#pragma unroll
    for (int i = 0; i < 2; ++i) {
      int idx = tid + i * 256;
      int row = idx >> 2, seg = idx & 3;
      int gr = rowBase + row;
      if (MODE == IN_F32) {
        float4 v0 = make_float4(0.f, 0.f, 0.f, 0.f), v1 = v0;
        if (gr < nrows) {
          v0 = *(const float4*)&Af[(size_t)gr * 128 + kc * 32 + seg * 8];
          v1 = *(const float4*)&Af[(size_t)gr * 128 + kc * 32 + seg * 8 + 4];
        }
        ushort4 h0, l0, h1, l1;
        split4h(v0, h0, l0);
        split4h(v1, h1, l1);
        *(ushort4*)&sAh[row * AST + seg * 8] = h0;
        *(ushort4*)&sAh[row * AST + seg * 8 + 4] = h1;
        *(ushort4*)&sAl[row * AST + seg * 8] = l0;
        *(ushort4*)&sAl[row * AST + seg * 8 + 4] = l1;
      } else {  // h1 is already fp16: exact A operand, pure copy
        uint4 raw = make_uint4(0, 0, 0, 0);
        if (gr < nrows)
          raw = *(const uint4*)&Af16[(size_t)gr * 128 + kc * 32 + seg * 8];
        *(uint4*)&sAh[row * AST + seg * 8] = raw;
      }
    }
    // stage B: 128 cols x 32 k (hi+lo); idx 0..511
#pragma unroll
    for (int i = 0; i < 2; ++i) {
      int idx = tid + i * 256;
      int col = idx >> 2, seg = idx & 3;
      *(uint4*)&sBh[col * AST + seg * 8] =
          *(const uint4*)&BTh[(size_t)(colBase + col) * 128 + kc * 32 + seg * 8];
      *(uint4*)&sBl[col * AST + seg * 8] =
          *(const uint4*)&BTl[(size_t)(colBase + col) * 128 + kc * 32 + seg * 8];
    }
    __syncthreads();

    f16x8 afh[4], afl[4], bfh[4], bfl[4];
#pragma unroll
    for (int m = 0; m < 4; ++m) {
      int r = rowHalf + m * 16 + l15;
      afh[m] = *(const f16x8*)&sAh[r * AST + quad * 8];
      if (MODE == IN_F32) afl[m] = *(const f16x8*)&sAl[r * AST + quad * 8];
    }
#pragma unroll
    for (int n = 0; n < 4; ++n) {
      int cc = colHalf + n * 16 + l15;
      bfh[n] = *(const f16x8*)&sBh[cc * AST + quad * 8];
      bfl[n] = *(const f16x8*)&sBl[cc * AST + quad * 8];
    }
    __builtin_amdgcn_s_setprio(1);
#pragma unroll
    for (int m = 0; m < 4; ++m)
#pragma unroll
      for (int n = 0; n < 4; ++n) {
        acc[m][n] = __builtin_amdgcn_mfma_f32_16x16x32_f16(afh[m], bfh[n], acc[m][n], 0, 0, 0);
        acc[m][n] = __builtin_amdgcn_mfma_f32_16x16x32_f16(afh[m], bfl[n], acc[m][n], 0, 0, 0);
        if (MODE == IN_F32)
          acc[m][n] = __builtin_amdgcn_mfma_f32_16x16x32_f16(afl[m], bfh[n], acc[m][n], 0, 0, 0);
      }
    __builtin_amdgcn_s_setprio(0);
    __syncthreads();
  }

  // ---- coalesced C epilogue: stage fp16 tile in (dead) smem ----
  unsigned short* sC = smem;
#pragma unroll
  for (int m = 0; m < 4; ++m)
#pragma unroll
    for (int r = 0; r < 4; ++r) {
      int lrow = rowHalf + m * 16 + quad * 4 + r;
#pragma unroll
      for (int n = 0; n < 4; ++n)
        sC[lrow * CST + colHalf + n * 16 + l15] =
            __half_as_ushort(__float2half(acc[m][n][r]));
    }
  __syncthreads();
  __half* __restrict__ C = (by == 0) ? Cl : Cr;
#pragma unroll
  for (int p = 0; p < 8; ++p) {
    int lrow = p * 16 + (tid >> 4);
    int grow = rowBase + lrow;
    if (grow < nrows) {
      uint4 v = *(const uint4*)&sC[lrow * CST + (tid & 15) * 8];
      *(uint4*)&C[(size_t)grow * 128 + (tid & 15) * 8] = v;
    }
  }
}

// ------------------------------ attention ----------------------------------
// R10-proven form. One wave per node; 16 lanes/edge (8 ch/lane, one b128
// fp16 load); 4 edge-slots/wave. Main loop 16 edges/iter, tail 4 edges/iter.
// Self loop lives in csr (csr[beg] = node). Outputs fp32 and/or fp16.
__global__ __launch_bounds__(256) void gat_attn(const __half* __restrict__ xl,
                                                const __half* __restrict__ xr,
                                                const int* __restrict__ row_start,
                                                const int* __restrict__ csr,
                                                const float* __restrict__ att,
                                                const float* __restrict__ bias,
                                                float* __restrict__ ofp,
                                                __half* __restrict__ oh16,
                                                int n_nodes) {
  int node = blockIdx.x * 4 + (threadIdx.x >> 6);
  if (node >= n_nodes) return;
  int lane = threadIdx.x & 63;
  int slot = lane >> 4;
  int l15 = lane & 15;
  int c0 = l15 * 8;

  // xr row (fp16 -> fp32)
  float fxr[8];
  {
    uint4 raw = *(const uint4*)&xr[(size_t)node * 128 + c0];
    const __half* hp = (const __half*)&raw;
#pragma unroll
    for (int k = 0; k < 8; ++k) fxr[k] = __half2float(hp[k]);
  }
  // att row, pre-scaled: a06 = 0.6*log2e*a, a04 = 0.4*log2e*a
  float a06[8], a04[8];
  {
    float4 a0 = *(const float4*)&att[c0];
    float4 a1 = *(const float4*)&att[c0 + 4];
    float av[8] = {a0.x, a0.y, a0.z, a0.w, a1.x, a1.y, a1.z, a1.w};
    const float C06 = 0.6f * LOG2E, C04 = 0.4f * LOG2E;
#pragma unroll
    for (int k = 0; k < 8; ++k) { a06[k] = av[k] * C06; a04[k] = av[k] * C04; }
  }

  float acc[8];
#pragma unroll
  for (int k = 0; k < 8; ++k) acc[k] = 0.f;
  float lsum = 0.f;

#define EDGE_BODY(SRC, PVALID)                                                 \
  {                                                                            \
    uint4 raw = *(const uint4*)&xl[(size_t)(unsigned)(SRC)*128 + c0];          \
    const __half* hp = (const __half*)&raw;                                    \
    float e = 0.f;                                                             \
    _Pragma("unroll") for (int k = 0; k < 8; ++k) {                            \
      float t = __half2float(hp[k]) + fxr[k];                                  \
      e = fmaf(a06[k], t, e);                                                  \
      e = fmaf(a04[k], fabsf(t), e);                                           \
    }                                                                          \
    e += __shfl_xor(e, 1);                                                     \
    e += __shfl_xor(e, 2);                                                     \
    float p = (PVALID) ? __builtin_amdgcn_exp2f(e) : 0.f;                      \
    lsum += p;                                                                 \
    _Pragma("unroll") for (int k = 0; k < 8; ++k)                              \
        acc[k] = fmaf(p, __half2float(hp[k]), acc[k]);                         \
  }

  int beg = row_start[node], end = row_start[node + 1];
  int deg = end - beg;  // includes self
  int fullEnd = beg + (deg & ~15);

  for (int base = beg; base < fullEnd; base += 16) {
    int b0 = base + 4 * slot;
    int s0 = csr[b0], s1 = csr[b0 + 1], s2 = csr[b0 + 2], s3 = csr[b0 + 3];
    EDGE_BODY(s0, true);
    EDGE_BODY(s1, true);
    EDGE_BODY(s2, true);
    EDGE_BODY(s3, true);
  }
  for (int base = fullEnd; base < end; base += 4) {  // csr padded by 16
    int idx = base + slot;
    int src = csr[idx];
    EDGE_BODY(src, idx < end);
  }
#undef EDGE_BODY

  // merge the 4 slots (same channels live in lanes with equal l15)
  lsum += __shfl_xor(lsum, 16);
  lsum += __shfl_xor(lsum, 32);
#pragma unroll
  for (int k = 0; k < 8; ++k) {
    acc[k] += __shfl_xor(acc[k], 16);
    acc[k] += __shfl_xor(acc[k], 32);
  }

  if (slot == 0) {
    float4 b0v = *(const float4*)&bias[c0];
    float4 b1v = *(const float4*)&bias[c0 + 4];
    float bv[8] = {b0v.x, b0v.y, b0v.z, b0v.w, b1v.x, b1v.y, b1v.z, b1v.w};
    float inv = 1.f / (lsum + 1e-16f);
    float o[8];
#pragma unroll
    for (int k = 0; k < 8; ++k) {
      float v = fmaf(acc[k], inv, bv[k]);
      o[k] = fmaf(0.495f, fabsf(v), 0.505f * v);  // leaky 0.01
    }
    if (ofp) {
      *(float4*)&ofp[(size_t)node * 128 + c0] = make_float4(o[0], o[1], o[2], o[3]);
      *(float4*)&ofp[(size_t)node * 128 + c0 + 4] = make_float4(o[4], o[5], o[6], o[7]);
    }
    if (oh16) {
      ushort4 ha, hb;
      ha.x = __half_as_ushort(__float2half(o[0]));
      ha.y = __half_as_ushort(__float2half(o[1]));
      ha.z = __half_as_ushort(__float2half(o[2]));
      ha.w = __half_as_ushort(__float2half(o[3]));
      hb.x = __half_as_ushort(__float2half(o[4]));
      hb.y = __half_as_ushort(__float2half(o[5]));
      hb.z = __half_as_ushort(__float2half(o[6]));
      hb.w = __half_as_ushort(__float2half(o[7]));
      *(ushort4*)&oh16[(size_t)node * 128 + c0] = ha;
      *(ushort4*)&oh16[(size_t)node * 128 + c0 + 4] = hb;
    }
  }
}

// ------------------------------ classifier ---------------------------------
__global__ __launch_bounds__(256) void classifier_kernel(const float4* __restrict__ h4,
                                                         const float* __restrict__ Wc,
                                                         const float* __restrict__ bc,
                                                         float* __restrict__ logits,
                                                         int n) {
  __shared__ float sW[2048];
  __shared__ float sb[16];
  int t = threadIdx.x;
#pragma unroll
  for (int i = 0; i < 8; ++i) sW[t + i * 256] = Wc[t + i * 256];
  if (t < 16) sb[t] = bc[t];
  __syncthreads();
  int node = blockIdx.x * 256 + t;
  if (node >= n) return;
  float acc[16];
#pragma unroll
  for (int o = 0; o < 16; ++o) acc[o] = sb[o];
  for (int c4 = 0; c4 < 32; ++c4) {
    float4 hv = h4[(unsigned)node * 32 + c4];
    const float* w = &sW[c4 * 64];
#pragma unroll
    for (int o = 0; o < 16; ++o) {
      acc[o] = fmaf(hv.x, w[o], acc[o]);
      acc[o] = fmaf(hv.y, w[16 + o], acc[o]);
      acc[o] = fmaf(hv.z, w[32 + o], acc[o]);
      acc[o] = fmaf(hv.w, w[48 + o], acc[o]);
    }
  }
#pragma unroll
  for (int q = 0; q < 4; ++q)
    *(float4*)&logits[(size_t)node * 16 + q * 4] =
        make_float4(acc[q * 4], acc[q * 4 + 1], acc[q * 4 + 2], acc[q * 4 + 3]);
}

// ---------------------------------------------------------------------------

extern "C" void kernel_launch(void* const* d_in, const int* in_sizes, int n_in,
                              void* d_out, int out_size, void* d_ws, size_t ws_size,
                              hipStream_t stream) {
  const float* x    = (const float*)d_in[0];
  const int*   ei   = (const int*)d_in[1];
  const float* Wl1  = (const float*)d_in[3];
  const float* Wr1  = (const float*)d_in[4];
  const float* att1 = (const float*)d_in[5];
  const float* b1   = (const float*)d_in[6];
  const float* Wl2  = (const float*)d_in[7];
  const float* Wr2  = (const float*)d_in[8];
  const float* att2 = (const float*)d_in[9];
  const float* b2   = (const float*)d_in[10];
  const float* Wc   = (const float*)d_in[11];
  const float* bc   = (const float*)d_in[12];

  const int N = in_sizes[0] / 128;
  const int E = in_sizes[1] / 2;

  float* outp   = (float*)d_out;
  float* logits = outp;                   // N*16 fp32
  float* hout   = outp + (size_t)N * 16;  // N*128 fp32 region
  // h1 (fp16) staged in the hout region (overwritten by fp32 h2 later)
  __half* h1f16 = (__half*)hout;

  const int cap = E / 8 + 16384;  // per-slice bucket capacity (27+ sigma)

  char* ws = (char*)d_ws;
  __half* xlbuf = (__half*)ws;                ws += (size_t)N * 128 * 2;
  __half* xrbuf = (__half*)ws;                ws += (size_t)N * 128 * 2;
  unsigned short* WT1h = (unsigned short*)ws; ws += 256 * 128 * 2;
  unsigned short* WT1l = (unsigned short*)ws; ws += 256 * 128 * 2;
  unsigned short* WT2h = (unsigned short*)ws; ws += 256 * 128 * 2;
  unsigned short* WT2l = (unsigned short*)ws; ws += 256 * 128 * 2;
  int* cnt       = (int*)ws;                  ws += (size_t)N * 4;
  int* bucketCur = (int*)ws;                  ws += 8 * 4;           // after cnt (one memset)
  int* wpos      = (int*)ws;                  ws += (size_t)N * 4;
  int* bsum      = (int*)ws;                  ws += 256 * 4;
  int2* bucket   = (int2*)ws;                 ws += (size_t)8 * cap * 8;
  int* row_start = (int*)ws;                  ws += (size_t)(N + 1) * 4;
  int* csr       = (int*)ws;                  ws += (size_t)(E + N + 16) * 4;

  const int* esrc = ei;
  const int* edst = ei + E;

  int gN = (N + 255) / 256;
  int gAttn = (N + 3) / 4;
  int sliceSize = (N + 7) / 8;

  int nbx = (N + 127) / 128;
  int nGemm = nbx * 2;
  int groups = (NSCAT + 4) / 5;  // 231 -> covers >=128 chunks per slice
  int g2 = (nGemm + 3) / 4;
  if (g2 > groups) groups = g2;
  int gFused = groups * 9;

  // CSR build (self loops embedded: counts+1, csr[beg]=node)
  hipMemsetAsync(cnt, 0, (size_t)(N + 8) * 4, stream);  // cnt + bucketCur
  convert_count<<<256 + (E + EPB - 1) / EPB, 256, 0, stream>>>(
      Wl1, Wr1, Wl2, Wr2, WT1h, WT1l, WT2h, WT2l,
      esrc, edst, cnt, bucketCur, bucket, E, sliceSize, cap);
  scan_blk<<<gN, 256, 0, stream>>>(cnt, row_start, bsum, N);
  scan_add<<<gN, 256, 0, stream>>>(row_start, bsum, wpos, csr, N, E + N, gN);

  // layer 1 GEMM (fp32 x, fp16-split inline) fused with bucketed CSR scatter
  gemm_mfma<IN_F32, 1><<<gFused, 256, 0, stream>>>(
      x, nullptr, WT1h, WT1l, xlbuf, xrbuf, N,
      bucket, bucketCur, wpos, csr, cap);
  gat_attn<<<gAttn, 256, 0, stream>>>(xlbuf, xrbuf, row_start, csr, att1, b1,
                                      nullptr, h1f16, N);

  // layer 2 (h1 fp16 = exact A operand: no split, 2-term, 32KB LDS)
  gemm_mfma<IN_F16, 0><<<dim3(nbx, 2), 256, 0, stream>>>(
      nullptr, h1f16, WT2h, WT2l, xlbuf, xrbuf, N,
      nullptr, nullptr, nullptr, nullptr, 0);
  gat_attn<<<gAttn, 256, 0, stream>>>(xlbuf, xrbuf, row_start, csr, att2, b2,
                                      hout, nullptr, N);

  // classifier
  classifier_kernel<<<(N + 255) / 256, 256, 0, stream>>>((const float4*)hout, Wc, bc,
                                                         logits, N);
}

// Round 11
// 285.551 us; speedup vs baseline: 1.1168x; 1.0632x over previous
//
#include <hip/hip_runtime.h>
#include <hip/hip_fp16.h>

// ---------------------------------------------------------------------------
// GATv2 x2 + classifier. N=50000, E=800000, IN=128, HEADS=4, HID=32, OUT=16.
// R21: ATOMIC-FREE scatter. R20 falsified the C-store write-amplification
//      theory (WRITE unchanged with coalesced epilogue); re-analysis shows
//      the fused kernel is 90% stall and the ~27MB write excess + ~46-48us
//      floor track the 800K wpos atomicAdd RMWs (L2 atomic-pipe throughput),
//      unchanged since R10. Fix: the count pass ALREADY atomicAdds cnt[d]
//      per edge -- keep its return as the edge's rank within node d, pack it
//      into the bucket entry (y = dst | rk<<16; dst<2^16, rk<=maxdeg~45).
//      Scatter becomes bucket-load -> row_start[d] load -> plain store at
//      row_start[d]+1+rk, 4-deep batched. wpos deleted; fused kernel has
//      ZERO atomics. Single-variable experiment: fused drop => atomics were
//      the pole (H2); flat => gemm structure is the pole (H1, next target).
//      KEPT: R17 role-split fusion, fp16-split GEMM (R19), coalesced C
//      epilogue (R20, neutral), bucket pre-partition, merged scans,
//      R10-form attn + separate classifier, h1 fp16, setprio.
// ---------------------------------------------------------------------------

#define LOG2E 1.4426950408889634f
#define AST 40  // LDS row stride in shorts (80B rows; fragment reads 2-way=free)

typedef _Float16 f16x8 __attribute__((ext_vector_type(8)));
typedef float f32x4 __attribute__((ext_vector_type(4)));

__device__ __forceinline__ unsigned short f2bf(float f) {
  union { float f; unsigned u; } x; x.f = f;
  unsigned r = x.u + 0x7fffu + ((x.u >> 16) & 1u);
  return (unsigned short)(r >> 16);
}
__device__ __forceinline__ float bf2f(unsigned short h) {
  union { unsigned u; float f; } x; x.u = ((unsigned)h) << 16;
  return x.f;
}
// fp16 hi/lo split: v = hi + lo + O(2^-22 * v)
__device__ __forceinline__ void split4h(float4 v, ushort4& h, ushort4& l) {
  __half hx = __float2half(v.x), hy = __float2half(v.y);
  __half hz = __float2half(v.z), hw = __float2half(v.w);
  h.x = __half_as_ushort(hx); l.x = __half_as_ushort(__float2half(v.x - __half2float(hx)));
  h.y = __half_as_ushort(hy); l.y = __half_as_ushort(__float2half(v.y - __half2float(hy)));
  h.z = __half_as_ushort(hz); l.z = __half_as_ushort(__float2half(v.z - __half2float(hz)));
  h.w = __half_as_ushort(hw); l.w = __half_as_ushort(__float2half(v.w - __half2float(hw)));
}

// ------------------------------ CSR build ----------------------------------

// per-block scan of (cnt[i]+1)  (+1 = self loop slot)
__global__ __launch_bounds__(256) void scan_blk(const int* __restrict__ cnt,
                                                int* __restrict__ excl,
                                                int* __restrict__ bsum, int n) {
  __shared__ int s[256];
  int t = threadIdx.x, i = blockIdx.x * 256 + t;
  int v = (i < n) ? (cnt[i] + 1) : 0;
  s[t] = v;
  __syncthreads();
#pragma unroll
  for (int off = 1; off < 256; off <<= 1) {
    int u = (t >= off) ? s[t - off] : 0;
    __syncthreads();
    s[t] += u;
    __syncthreads();
  }
  if (i < n) excl[i] = s[t] - v;
  if (t == 255) bsum[blockIdx.x] = s[255];
}

// merged bsum-scan + add: each block scans bsum[0..nb) in LDS (nb<=256),
// takes its own exclusive prefix; writes row_start/self-loop; block 0
// also writes row_start[n] (total) and zeroes the csr pad.
__global__ __launch_bounds__(256) void scan_add(int* __restrict__ row_start,
                                                const int* __restrict__ bsum,
                                                int* __restrict__ csr,
                                                int n, int padBase, int nb) {
  __shared__ int s[256];
  int t = threadIdx.x;
  int v = (t < nb) ? bsum[t] : 0;
  s[t] = v;
  __syncthreads();
#pragma unroll
  for (int off = 1; off < 256; off <<= 1) {
    int u = (t >= off) ? s[t - off] : 0;
    __syncthreads();
    s[t] += u;
    __syncthreads();
  }
  int pref = (blockIdx.x > 0) ? s[blockIdx.x - 1] : 0;
  int i = blockIdx.x * 256 + t;
  if (i < n) {
    int r = row_start[i] + pref;
    row_start[i] = r;
    csr[r] = i;  // self loop first in each row
  }
  if (blockIdx.x == 0) {
    if (t == 0) row_start[n] = s[nb - 1];
    if (t < 16) csr[padBase + t] = 0;
  }
}

// ------------- weight convert + degree count + slice bucketing -------------
// blocks 0..255: split-fp16 weight transpose (both layers)
// blocks 256.. : 1024 edges each: degree count (atomicAdd return = the
//                edge's RANK within its dst node, packed into the bucket
//                entry) + append (src, dst|rk<<16) to the dst-slice bucket.
#define EPB 1024
__global__ __launch_bounds__(256) void convert_count(
    const float* __restrict__ Wl1, const float* __restrict__ Wr1,
    const float* __restrict__ Wl2, const float* __restrict__ Wr2,
    unsigned short* __restrict__ BT1h, unsigned short* __restrict__ BT1l,
    unsigned short* __restrict__ BT2h, unsigned short* __restrict__ BT2l,
    const int* __restrict__ esrc, const int* __restrict__ edst,
    int* __restrict__ cnt, int* __restrict__ bucketCur,
    int2* __restrict__ bucket, int E, int sliceSize, int cap) {
  int b = blockIdx.x;
  int t = threadIdx.x;
  if (b >= 256) {
    __shared__ int bcnt[8], bbase[8];
    if (t < 8) bcnt[t] = 0;
    __syncthreads();
    int base = (b - 256) * EPB;
    int sl[4], rk[4], pv[4], sv[4];
#pragma unroll
    for (int j = 0; j < 4; ++j) {
      int i = base + t + j * 256;
      bool v = (i < E);
      int d = v ? edst[i] : 0;
      sv[j] = v ? esrc[i] : 0;
      int s = d / sliceSize;  // 0..7
      sl[j] = v ? s : -1;
      if (v) {
        int nodeRank = atomicAdd(&cnt[d], 1);    // rank of edge within node d
        pv[j] = d | (nodeRank << 16);            // dst<2^16, rank<2^16
        rk[j] = atomicAdd(&bcnt[s], 1);
      }
    }
    __syncthreads();
    if (t < 8 && bcnt[t] > 0) bbase[t] = atomicAdd(&bucketCur[t], bcnt[t]);
    __syncthreads();
#pragma unroll
    for (int j = 0; j < 4; ++j) {
      if (sl[j] >= 0) {
        int pos = sl[j] * cap + bbase[sl[j]] + rk[j];
        bucket[pos] = make_int2(sv[j], pv[j]);
      }
    }
    return;
  }
  const float* Wl = (b < 128) ? Wl1 : Wl2;
  const float* Wr = (b < 128) ? Wr1 : Wr2;
  unsigned short* BTh = (b < 128) ? BT1h : BT2h;
  unsigned short* BTl = (b < 128) ? BT1l : BT2l;
  int idx = (b & 127) * 256 + t;  // 0..32767
  int col = idx >> 7, k = idx & 127;
  float v = (col < 128) ? Wl[k * 128 + col] : Wr[k * 128 + (col - 128)];
  __half h = __float2half(v);
  BTh[idx] = __half_as_ushort(h);
  BTl[idx] = __half_as_ushort(__float2half(v - __half2float(h)));
}

// ------------------------ MFMA GEMM (+fused scatter) -----------------------
// C[N x 256] = A[N x 128] @ W[128 x 256], split-fp16; C stored fp16.
// IN_F32: A split to fp16 hi/lo (residual 2^-22), 3 MFMA terms, 40KB LDS.
// IN_F16: A exact fp16 (no split, pure copies), 2 MFMA terms, 32KB LDS.
// Block = 128 rows x 128 cols. 4 waves, each 64x64 (16 acc tiles).
// Epilogue: C-tile staged fp16 in (dead) smem, stored coalesced.
// FUSE=1: grid also carries scatter blocks (5 of every 9). Scatter slice is
// the REAL blockIdx&7 (== XCD); ATOMIC-FREE: csr position is
// row_start[dst]+1+rank (rank pre-computed in count pass).
enum { IN_F32 = 0, IN_F16 = 1 };
#define NSCAT 1152
#define NCHUNK 128
template <int MODE, int FUSE>
__global__ __launch_bounds__(256) void gemm_mfma(
    const float* __restrict__ Af, const __half* __restrict__ Af16,
    const unsigned short* __restrict__ BTh, const unsigned short* __restrict__ BTl,
    __half* __restrict__ Cl, __half* __restrict__ Cr, int nrows,
    const int2* __restrict__ bucket, const int* __restrict__ bucketCur,
    const int* __restrict__ row_start, int* __restrict__ csr, int cap) {
  constexpr int NBUF = (MODE == IN_F16) ? 3 : 4;
  constexpr int CST = (MODE == IN_F32) ? 132 : 128;  // C-tile row stride
  constexpr int SMEMN = (NBUF * 128 * AST > 128 * CST) ? NBUF * 128 * AST
                                                       : 128 * CST;
  __shared__ __align__(16) unsigned short smem[SMEMN];
  int tid = threadIdx.x;
  int bx, by;
  if (FUSE) {
    int g = blockIdx.x / 9, r = blockIdx.x - g * 9;
    if (r < 5) {  // ---- scatter role (atomic-free) ----
      int sid = g * 5 + r;
      if (sid < NSCAT) {
        int slice = blockIdx.x & 7;  // == XCD (round-robin dispatch)
        // rank among scatter blocks with the same slice, ordered by g:
        int chunk = (g >> 3) * 5;
        for (int gp = g & ~7; gp < g; ++gp)
          chunk += (((slice - gp) & 7) < 5) ? 1 : 0;
        if (chunk < NCHUNK) {
          int cntS = bucketCur[slice];
          int per = (cntS + NCHUNK - 1) / NCHUNK;
          int b0 = chunk * per;
          int ee = min(b0 + per, cntS);
          const int2* bk = bucket + (size_t)slice * cap;
          for (int i = b0 + tid; i < ee; i += 1024) {  // 4-deep MLP batch
            bool v1 = i + 256 < ee, v2 = i + 512 < ee, v3 = i + 768 < ee;
            int2 e0 = bk[i];
            int2 e1 = v1 ? bk[i + 256] : make_int2(0, 0);
            int2 e2 = v2 ? bk[i + 512] : make_int2(0, 0);
            int2 e3 = v3 ? bk[i + 768] : make_int2(0, 0);
            int d0 = e0.y & 0xFFFF, r0 = (int)((unsigned)e0.y >> 16);
            int d1 = e1.y & 0xFFFF, r1 = (int)((unsigned)e1.y >> 16);
            int d2 = e2.y & 0xFFFF, r2 = (int)((unsigned)e2.y >> 16);
            int d3 = e3.y & 0xFFFF, r3 = (int)((unsigned)e3.y >> 16);
            int p0 = row_start[d0] + 1 + r0;
            int p1 = v1 ? row_start[d1] + 1 + r1 : 0;
            int p2 = v2 ? row_start[d2] + 1 + r2 : 0;
            int p3 = v3 ? row_start[d3] + 1 + r3 : 0;
            csr[p0] = e0.x;
            if (v1) csr[p1] = e1.x;
            if (v2) csr[p2] = e2.x;
            if (v3) csr[p3] = e3.x;
          }
        }
      }
      return;
    }
    int gid = g * 4 + (r - 5);  // ---- gemm role ----
    int nbx = (nrows + 127) >> 7;
    if (gid >= nbx * 2) return;
    bx = gid >> 1;
    by = gid & 1;
  } else {
    bx = blockIdx.x;
    by = blockIdx.y;
  }

  constexpr int ABUF = 128 * AST;  // 5120 shorts
  unsigned short* sAh = smem;
  unsigned short* sAl = (MODE == IN_F32) ? smem + ABUF : nullptr;
  unsigned short* sBh = smem + ((MODE == IN_F32) ? 2 * ABUF : ABUF);
  unsigned short* sBl = smem + ((MODE == IN_F32) ? 3 * ABUF : 2 * ABUF);

  int wave = tid >> 6, lane = tid & 63;
  int rowBase = bx * 128;
  int colBase = by * 128;
  int rowHalf = (wave >> 1) * 64;
  int colHalf = (wave & 1) * 64;
  int l15 = lane & 15, quad = lane >> 4;

  f32x4 acc[4][4];
#pragma unroll
  for (int m = 0; m < 4; ++m)
#pragma unroll
    for (int n = 0; n < 4; ++n) acc[m][n] = (f32x4){0.f, 0.f, 0.f, 0.f};

  for (int kc = 0; kc < 4; ++kc) {
    // stage A: 128 rows x 32 k; idx 0..511, 8 k-elems each
#pragma unroll
    for (int i = 0; i < 2; ++i) {
      int idx = tid + i * 256;
      int row = idx >> 2, seg = idx & 3;
      int gr = rowBase + row;
      if (MODE == IN_F32) {
        float4 v0 = make_float4(0.f, 0.f, 0.f, 0.f), v1 = v0;
        if (gr < nrows) {
          v0 = *(const float4*)&Af[(size_t)gr * 128 + kc * 32 + seg * 8];
          v1 = *(const float4*)&Af[(size_t)gr * 128 + kc * 32 + seg * 8 + 4];
        }
        ushort4 h0, l0, h1, l1;
        split4h(v0, h0, l0);
        split4h(v1, h1, l1);
        *(ushort4*)&sAh[row * AST + seg * 8] = h0;
        *(ushort4*)&sAh[row * AST + seg * 8 + 4] = h1;
        *(ushort4*)&sAl[row * AST + seg * 8] = l0;
        *(ushort4*)&sAl[row * AST + seg * 8 + 4] = l1;
      } else {  // h1 is already fp16: exact A operand, pure copy
        uint4 raw = make_uint4(0, 0, 0, 0);
        if (gr < nrows)
          raw = *(const uint4*)&Af16[(size_t)gr * 128 + kc * 32 + seg * 8];
        *(uint4*)&sAh[row * AST + seg * 8] = raw;
      }
    }
    // stage B: 128 cols x 32 k (hi+lo); idx 0..511
#pragma unroll
    for (int i = 0; i < 2; ++i) {
      int idx = tid + i * 256;
      int col = idx >> 2, seg = idx & 3;
      *(uint4*)&sBh[col * AST + seg * 8] =
          *(const uint4*)&BTh[(size_t)(colBase + col) * 128 + kc * 32 + seg * 8];
      *(uint4*)&sBl[col * AST + seg * 8] =
          *(const uint4*)&BTl[(size_t)(colBase + col) * 128 + kc * 32 + seg * 8];
    }
    __syncthreads();

    f16x8 afh[4], afl[4], bfh[4], bfl[4];
#pragma unroll
    for (int m = 0; m < 4; ++m) {
      int r = rowHalf + m * 16 + l15;
      afh[m] = *(const f16x8*)&sAh[r * AST + quad * 8];
      if (MODE == IN_F32) afl[m] = *(const f16x8*)&sAl[r * AST + quad * 8];
    }
#pragma unroll
    for (int n = 0; n < 4; ++n) {
      int cc = colHalf + n * 16 + l15;
      bfh[n] = *(const f16x8*)&sBh[cc * AST + quad * 8];
      bfl[n] = *(const f16x8*)&sBl[cc * AST + quad * 8];
    }
    __builtin_amdgcn_s_setprio(1);
#pragma unroll
    for (int m = 0; m < 4; ++m)
#pragma unroll
      for (int n = 0; n < 4; ++n) {
        acc[m][n] = __builtin_amdgcn_mfma_f32_16x16x32_f16(afh[m], bfh[n], acc[m][n], 0, 0, 0);
        acc[m][n] = __builtin_amdgcn_mfma_f32_16x16x32_f16(afh[m], bfl[n], acc[m][n], 0, 0, 0);
        if (MODE == IN_F32)
          acc[m][n] = __builtin_amdgcn_mfma_f32_16x16x32_f16(afl[m], bfh[n], acc[m][n], 0, 0, 0);
      }
    __builtin_amdgcn_s_setprio(0);
    __syncthreads();
  }

  // ---- coalesced C epilogue: stage fp16 tile in (dead) smem ----
  unsigned short* sC = smem;
#pragma unroll
  for (int m = 0; m < 4; ++m)
#pragma unroll
    for (int r = 0; r < 4; ++r) {
      int lrow = rowHalf + m * 16 + quad * 4 + r;
#pragma unroll
      for (int n = 0; n < 4; ++n)
        sC[lrow * CST + colHalf + n * 16 + l15] =
            __half_as_ushort(__float2half(acc[m][n][r]));
    }
  __syncthreads();
  __half* __restrict__ C = (by == 0) ? Cl : Cr;
#pragma unroll
  for (int p = 0; p < 8; ++p) {
    int lrow = p * 16 + (tid >> 4);
    int grow = rowBase + lrow;
    if (grow < nrows) {
      uint4 v = *(const uint4*)&sC[lrow * CST + (tid & 15) * 8];
      *(uint4*)&C[(size_t)grow * 128 + (tid & 15) * 8] = v;
    }
  }
}

// ------------------------------ attention ----------------------------------
// R10-proven form. One wave per node; 16 lanes/edge (8 ch/lane, one b128
// fp16 load); 4 edge-slots/wave. Main loop 16 edges/iter, tail 4 edges/iter.
// Self loop lives in csr (csr[beg] = node). Outputs fp32 and/or fp16.
__global__ __launch_bounds__(256) void gat_attn(const __half* __restrict__ xl,
                                                const __half* __restrict__ xr,
                                                const int* __restrict__ row_start,
                                                const int* __restrict__ csr,
                                                const float* __restrict__ att,
                                                const float* __restrict__ bias,
                                                float* __restrict__ ofp,
                                                __half* __restrict__ oh16,
                                                int n_nodes) {
  int node = blockIdx.x * 4 + (threadIdx.x >> 6);
  if (node >= n_nodes) return;
  int lane = threadIdx.x & 63;
  int slot = lane >> 4;
  int l15 = lane & 15;
  int c0 = l15 * 8;

  // xr row (fp16 -> fp32)
  float fxr[8];
  {
    uint4 raw = *(const uint4*)&xr[(size_t)node * 128 + c0];
    const __half* hp = (const __half*)&raw;
#pragma unroll
    for (int k = 0; k < 8; ++k) fxr[k] = __half2float(hp[k]);
  }
  // att row, pre-scaled: a06 = 0.6*log2e*a, a04 = 0.4*log2e*a
  float a06[8], a04[8];
  {
    float4 a0 = *(const float4*)&att[c0];
    float4 a1 = *(const float4*)&att[c0 + 4];
    float av[8] = {a0.x, a0.y, a0.z, a0.w, a1.x, a1.y, a1.z, a1.w};
    const float C06 = 0.6f * LOG2E, C04 = 0.4f * LOG2E;
#pragma unroll
    for (int k = 0; k < 8; ++k) { a06[k] = av[k] * C06; a04[k] = av[k] * C04; }
  }

  float acc[8];
#pragma unroll
  for (int k = 0; k < 8; ++k) acc[k] = 0.f;
  float lsum = 0.f;

#define EDGE_BODY(SRC, PVALID)                                                 \
  {                                                                            \
    uint4 raw = *(const uint4*)&xl[(size_t)(unsigned)(SRC)*128 + c0];          \
    const __half* hp = (const __half*)&raw;                                    \
    float e = 0.f;                                                             \
    _Pragma("unroll") for (int k = 0; k < 8; ++k) {                            \
      float t = __half2float(hp[k]) + fxr[k];                                  \
      e = fmaf(a06[k], t, e);                                                  \
      e = fmaf(a04[k], fabsf(t), e);                                           \
    }                                                                          \
    e += __shfl_xor(e, 1);                                                     \
    e += __shfl_xor(e, 2);                                                     \
    float p = (PVALID) ? __builtin_amdgcn_exp2f(e) : 0.f;                      \
    lsum += p;                                                                 \
    _Pragma("unroll") for (int k = 0; k < 8; ++k)                              \
        acc[k] = fmaf(p, __half2float(hp[k]), acc[k]);                         \
  }

  int beg = row_start[node], end = row_start[node + 1];
  int deg = end - beg;  // includes self
  int fullEnd = beg + (deg & ~15);

  for (int base = beg; base < fullEnd; base += 16) {
    int b0 = base + 4 * slot;
    int s0 = csr[b0], s1 = csr[b0 + 1], s2 = csr[b0 + 2], s3 = csr[b0 + 3];
    EDGE_BODY(s0, true);
    EDGE_BODY(s1, true);
    EDGE_BODY(s2, true);
    EDGE_BODY(s3, true);
  }
  for (int base = fullEnd; base < end; base += 4) {  // csr padded by 16
    int idx = base + slot;
    int src = csr[idx];
    EDGE_BODY(src, idx < end);
  }
#undef EDGE_BODY

  // merge the 4 slots (same channels live in lanes with equal l15)
  lsum += __shfl_xor(lsum, 16);
  lsum += __shfl_xor(lsum, 32);
#pragma unroll
  for (int k = 0; k < 8; ++k) {
    acc[k] += __shfl_xor(acc[k], 16);
    acc[k] += __shfl_xor(acc[k], 32);
  }

  if (slot == 0) {
    float4 b0v = *(const float4*)&bias[c0];
    float4 b1v = *(const float4*)&bias[c0 + 4];
    float bv[8] = {b0v.x, b0v.y, b0v.z, b0v.w, b1v.x, b1v.y, b1v.z, b1v.w};
    float inv = 1.f / (lsum + 1e-16f);
    float o[8];
#pragma unroll
    for (int k = 0; k < 8; ++k) {
      float v = fmaf(acc[k], inv, bv[k]);
      o[k] = fmaf(0.495f, fabsf(v), 0.505f * v);  // leaky 0.01
    }
    if (ofp) {
      *(float4*)&ofp[(size_t)node * 128 + c0] = make_float4(o[0], o[1], o[2], o[3]);
      *(float4*)&ofp[(size_t)node * 128 + c0 + 4] = make_float4(o[4], o[5], o[6], o[7]);
    }
    if (oh16) {
      ushort4 ha, hb;
      ha.x = __half_as_ushort(__float2half(o[0]));
      ha.y = __half_as_ushort(__float2half(o[1]));
      ha.z = __half_as_ushort(__float2half(o[2]));
      ha.w = __half_as_ushort(__float2half(o[3]));
      hb.x = __half_as_ushort(__float2half(o[4]));
      hb.y = __half_as_ushort(__float2half(o[5]));
      hb.z = __half_as_ushort(__float2half(o[6]));
      hb.w = __half_as_ushort(__float2half(o[7]));
      *(ushort4*)&oh16[(size_t)node * 128 + c0] = ha;
      *(ushort4*)&oh16[(size_t)node * 128 + c0 + 4] = hb;
    }
  }
}

// ------------------------------ classifier ---------------------------------
__global__ __launch_bounds__(256) void classifier_kernel(const float4* __restrict__ h4,
                                                         const float* __restrict__ Wc,
                                                         const float* __restrict__ bc,
                                                         float* __restrict__ logits,
                                                         int n) {
  __shared__ float sW[2048];
  __shared__ float sb[16];
  int t = threadIdx.x;
#pragma unroll
  for (int i = 0; i < 8; ++i) sW[t + i * 256] = Wc[t + i * 256];
  if (t < 16) sb[t] = bc[t];
  __syncthreads();
  int node = blockIdx.x * 256 + t;
  if (node >= n) return;
  float acc[16];
#pragma unroll
  for (int o = 0; o < 16; ++o) acc[o] = sb[o];
  for (int c4 = 0; c4 < 32; ++c4) {
    float4 hv = h4[(unsigned)node * 32 + c4];
    const float* w = &sW[c4 * 64];
#pragma unroll
    for (int o = 0; o < 16; ++o) {
      acc[o] = fmaf(hv.x, w[o], acc[o]);
      acc[o] = fmaf(hv.y, w[16 + o], acc[o]);
      acc[o] = fmaf(hv.z, w[32 + o], acc[o]);
      acc[o] = fmaf(hv.w, w[48 + o], acc[o]);
    }
  }
#pragma unroll
  for (int q = 0; q < 4; ++q)
    *(float4*)&logits[(size_t)node * 16 + q * 4] =
        make_float4(acc[q * 4], acc[q * 4 + 1], acc[q * 4 + 2], acc[q * 4 + 3]);
}

// ---------------------------------------------------------------------------

extern "C" void kernel_launch(void* const* d_in, const int* in_sizes, int n_in,
                              void* d_out, int out_size, void* d_ws, size_t ws_size,
                              hipStream_t stream) {
  const float* x    = (const float*)d_in[0];
  const int*   ei   = (const int*)d_in[1];
  const float* Wl1  = (const float*)d_in[3];
  const float* Wr1  = (const float*)d_in[4];
  const float* att1 = (const float*)d_in[5];
  const float* b1   = (const float*)d_in[6];
  const float* Wl2  = (const float*)d_in[7];
  const float* Wr2  = (const float*)d_in[8];
  const float* att2 = (const float*)d_in[9];
  const float* b2   = (const float*)d_in[10];
  const float* Wc   = (const float*)d_in[11];
  const float* bc   = (const float*)d_in[12];

  const int N = in_sizes[0] / 128;
  const int E = in_sizes[1] / 2;

  float* outp   = (float*)d_out;
  float* logits = outp;                   // N*16 fp32
  float* hout   = outp + (size_t)N * 16;  // N*128 fp32 region
  // h1 (fp16) staged in the hout region (overwritten by fp32 h2 later)
  __half* h1f16 = (__half*)hout;

  const int cap = E / 8 + 16384;  // per-slice bucket capacity (27+ sigma)

  char* ws = (char*)d_ws;
  __half* xlbuf = (__half*)ws;                ws += (size_t)N * 128 * 2;
  __half* xrbuf = (__half*)ws;                ws += (size_t)N * 128 * 2;
  unsigned short* WT1h = (unsigned short*)ws; ws += 256 * 128 * 2;
  unsigned short* WT1l = (unsigned short*)ws; ws += 256 * 128 * 2;
  unsigned short* WT2h = (unsigned short*)ws; ws += 256 * 128 * 2;
  unsigned short* WT2l = (unsigned short*)ws; ws += 256 * 128 * 2;
  int* cnt       = (int*)ws;                  ws += (size_t)N * 4;
  int* bucketCur = (int*)ws;                  ws += 8 * 4;           // after cnt (one memset)
  int* bsum      = (int*)ws;                  ws += 256 * 4;
  int2* bucket   = (int2*)ws;                 ws += (size_t)8 * cap * 8;
  int* row_start = (int*)ws;                  ws += (size_t)(N + 1) * 4;
  int* csr       = (int*)ws;                  ws += (size_t)(E + N + 16) * 4;

  const int* esrc = ei;
  const int* edst = ei + E;

  int gN = (N + 255) / 256;
  int gAttn = (N + 3) / 4;
  int sliceSize = (N + 7) / 8;

  int nbx = (N + 127) / 128;
  int nGemm = nbx * 2;
  int groups = (NSCAT + 4) / 5;  // 231 -> covers >=128 chunks per slice
  int g2 = (nGemm + 3) / 4;
  if (g2 > groups) groups = g2;
  int gFused = groups * 9;

  // CSR build (self loops embedded: counts+1, csr[beg]=node)
  hipMemsetAsync(cnt, 0, (size_t)(N + 8) * 4, stream);  // cnt + bucketCur
  convert_count<<<256 + (E + EPB - 1) / EPB, 256, 0, stream>>>(
      Wl1, Wr1, Wl2, Wr2, WT1h, WT1l, WT2h, WT2l,
      esrc, edst, cnt, bucketCur, bucket, E, sliceSize, cap);
  scan_blk<<<gN, 256, 0, stream>>>(cnt, row_start, bsum, N);
  scan_add<<<gN, 256, 0, stream>>>(row_start, bsum, csr, N, E + N, gN);

  // layer 1 GEMM (fp32 x, fp16-split inline) fused with atomic-free scatter
  gemm_mfma<IN_F32, 1><<<gFused, 256, 0, stream>>>(
      x, nullptr, WT1h, WT1l, xlbuf, xrbuf, N,
      bucket, bucketCur, row_start, csr, cap);
  gat_attn<<<gAttn, 256, 0, stream>>>(xlbuf, xrbuf, row_start, csr, att1, b1,
                                      nullptr, h1f16, N);

  // layer 2 (h1 fp16 = exact A operand: no split, 2-term, 32KB LDS)
  gemm_mfma<IN_F16, 0><<<dim3(nbx, 2), 256, 0, stream>>>(
      nullptr, h1f16, WT2h, WT2l, xlbuf, xrbuf, N,
      nullptr, nullptr, nullptr, nullptr, 0);
  gat_attn<<<gAttn, 256, 0, stream>>>(xlbuf, xrbuf, row_start, csr, att2, b2,
                                      hout, nullptr, N);

  // classifier
  classifier_kernel<<<(N + 255) / 256, 256, 0, stream>>>((const float4*)hout, Wc, bc,
                                                         logits, N);
}